// Round 7
// baseline (226.447 us; speedup 1.0000x reference)
//
#include <hip/hip_runtime.h>
#include <stdint.h>

#define B_ 16
#define H_ 64
#define W_ 64
#define D_ 64
#define C_ 16
#define K_ 5
#define N_ 4096
#define NC_ 64         // attention n-chunks
#define CS_ 64         // chunk size = N_/NC_ (one wave per chunk-row-set)
#define EPS 1e-5f

typedef __attribute__((ext_vector_type(8))) short bf16x8;
typedef __attribute__((ext_vector_type(4))) float f32x4;

__device__ __forceinline__ float wsum64(float v){
  #pragma unroll
  for(int o=1;o<64;o<<=1) v += __shfl_xor(v,o,64);
  return v;
}
__device__ __forceinline__ float wmax64(float v){
  #pragma unroll
  for(int o=1;o<64;o<<=1) v = fmaxf(v, __shfl_xor(v,o,64));
  return v;
}
__device__ __forceinline__ float wmin64(float v){
  #pragma unroll
  for(int o=1;o<64;o<<=1) v = fminf(v, __shfl_xor(v,o,64));
  return v;
}
__device__ __forceinline__ uint16_t f2bf(float f){
  uint32_t u = __float_as_uint(f);
  u += 0x7fffu + ((u>>16)&1u);
  return (uint16_t)(u>>16);
}

// k_pre: fgpos (0-4) + folded biases (5) + fvb/wgx/wgy/gscal/out_slot-zero (6)
// + wrpT (7-22) + gw (23-118) + slot init (119-138)
// + q-side collapse WQ/bq2/vq/csc (139) + gru-side collapse WC/uvec (140)
// Collapse matmuls 4x4 register-blocked; finishers LDS-staged + wave-parallel.
__global__ __launch_bounds__(256) void k_pre(
    const float* __restrict__ mask, const float* __restrict__ noise,
    const float* __restrict__ mu, const float* __restrict__ lsg,
    const float* __restrict__ wm, const float* __restrict__ bm, const float* __restrict__ lnkb,
    const float* __restrict__ wk, const float* __restrict__ wv, const float* __restrict__ lnfb,
    const float* __restrict__ wq, const float* __restrict__ lnqg, const float* __restrict__ lnqb,
    const float* __restrict__ wres, const float* __restrict__ bres,
    const float* __restrict__ lnrg, const float* __restrict__ lnrb,
    const float* __restrict__ wih, const float* __restrict__ whh,
    const float* __restrict__ wg, const float* __restrict__ bg,
    const float* __restrict__ lnfg, const float* __restrict__ lnkg,
    float* __restrict__ ws_fg, float* __restrict__ out_fg,
    float* __restrict__ bm2, float* __restrict__ fkb, float* __restrict__ fvb,
    float* __restrict__ qb, float* __restrict__ br2,
    float* __restrict__ wgx, float* __restrict__ wgy, float* __restrict__ gscal,
    float* __restrict__ wrpT,
    float* __restrict__ gw, float* __restrict__ slot, float* __restrict__ out_slot,
    float* __restrict__ WQp, float* __restrict__ WCp, float* __restrict__ bq2p,
    float* __restrict__ uvp, float* __restrict__ vqp, float* __restrict__ cscp){
  __shared__ __align__(16) float M0[64][68];
  __shared__ __align__(16) float M1[64][68];
  __shared__ __align__(16) float M2T[64][68];
  __shared__ float vtmp[4][64];
  __shared__ float aux[4][64];   // wgx, wgy, bg, lnkg staged from global
  int bid=blockIdx.x, tid=threadIdx.x;

  #define MM44(SRCA, SRCB) { \
    float a4[4], b4[4]; \
    *(float4*)a4 = *(const float4*)(SRCA); \
    *(float4*)b4 = *(const float4*)(SRCB); \
    _Pragma("unroll") \
    for(int ii=0;ii<4;ii++){ \
      _Pragma("unroll") \
      for(int jj=0;jj<4;jj++) acc[ii][jj]=fmaf(a4[ii],b4[jj],acc[ii][jj]); \
    } }

  if(bid<5){
    int k=bid;
    float sm=0.f, sx=0.f, sy=0.f;
    for(int p=tid; p<H_*W_; p+=256){
      int i=p>>6, j=p&63;
      float m = mask[k*H_*W_ + p];
      float x = -1.f + (2.f/63.f)*j;
      float y = -1.f + (2.f/63.f)*i;
      sm+=m; sx+=m*x; sy+=m*y;
    }
    __shared__ float r0[4], r1[4], r2[4];
    int wid=tid>>6, lane=tid&63;
    sm=wsum64(sm); sx=wsum64(sx); sy=wsum64(sy);
    if(lane==0){ r0[wid]=sm; r1[wid]=sx; r2[wid]=sy; }
    __syncthreads();
    if(tid==0){
      float tm=r0[0]+r0[1]+r0[2]+r0[3];
      float tx=r1[0]+r1[1]+r1[2]+r1[3];
      float ty=r2[0]+r2[1]+r2[2]+r2[3];
      float px = tx/(tm+1e-5f), py = ty/(tm+1e-5f);
      ws_fg[k*2+0]=px; ws_fg[k*2+1]=py;
      for(int b=0;b<B_;b++){ out_fg[(b*K_+k)*2+0]=px; out_fg[(b*K_+k)*2+1]=py; }
    }
  } else if(bid==5){
    int sel=tid>>6, o=tid&63; float s=0.f;
    if(sel==0){ s=bm[o]; for(int d=0;d<64;d++) s+=lnkb[d]*wm[o*64+d]; bm2[o]=s; }
    else if(sel==1){ for(int d=0;d<64;d++) s+=lnqb[d]*wq[o*64+d]; qb[o]=0.125f*s; }
    else if(sel==2){ for(int d=0;d<64;d++) s+=lnrb[d]*wres[o*64+d]; br2[o]=s+bres[o]; }
    else { for(int d=0;d<64;d++) s+=lnfb[d]*wk[o*64+d]; fkb[o]=s; }
  } else if(bid==6){
    int wv4=tid>>6, l=tid&63;
    if(wv4==0){ float s=0.f; for(int d=0;d<64;d++) s+=lnfb[d]*wv[l*64+d]; fvb[l]=s; }
    else if(wv4==1){
      float4 w4 = *(const float4*)(wg + l*4);
      wgx[l]=w4.x-w4.z; wgy[l]=w4.y-w4.w;
    } else if(wv4==2){
      float4 w4 = *(const float4*)(wg + l*4);
      float wx=w4.x-w4.z, wy=w4.y-w4.w, bl=bg[l];
      float t;
      t=wsum64(wx);    if(l==0) gscal[0]=t*(1.f/64.f);
      t=wsum64(wy);    if(l==0) gscal[1]=t*(1.f/64.f);
      t=wsum64(bl);    if(l==0) gscal[2]=t*(1.f/64.f);
      t=wsum64(wx*wx); if(l==0) gscal[3]=t*(1.f/64.f);
      t=wsum64(wy*wy); if(l==0) gscal[4]=t*(1.f/64.f);
      t=wsum64(wx*wy); if(l==0) gscal[5]=t*(2.f/64.f);
      t=wsum64(wx*bl); if(l==0) gscal[6]=t*(2.f/64.f);
      t=wsum64(wy*bl); if(l==0) gscal[7]=t*(2.f/64.f);
      t=wsum64(bl*bl); if(l==0) gscal[8]=t*(1.f/64.f);
    } else {
      for(int j=l;j<B_*K_*16;j+=64){ int bk2=j>>4, cc2=j&15; out_slot[bk2*80+64+cc2]=0.f; }
    }
  } else if(bid<23){
    int i=(bid-7)*256+tid;           // < 4096
    int d=i>>6, o=i&63;
    wrpT[i]=lnrg[d]*wres[o*64+d];
  } else if(bid<119){
    int i=(bid-23)*256+tid;          // < 24576
    int g6=i>>12, r=i&4095, d=r>>6, o=r&63;
    float v = (g6<3)? wih[(g6*64+o)*64+d] : whh[((g6-3)*64+o)*64+d];
    gw[g6*4096 + d*64 + o] = v;
  } else if(bid<139){
    int i=(bid-119)*256+tid;
    if(i<B_*K_*D_){ int d=i&63; slot[i]=mu[d]+expf(lsg[d])*noise[i]; }
  } else if(bid==139){
    // q-side collapse: WQ = (0.125*lnqg ∘ wq^T @ wm) @ (lnkg ∘ wk) ∘ lnfg
    for(int i=tid;i<4096;i+=256){ int r=i>>6,c2=i&63; M0[r][c2]=wq[i]; M1[r][c2]=wm[i]; }
    if(tid>=192){ int l=tid-192;
      float4 w4 = *(const float4*)(wg + l*4);
      aux[0][l]=w4.x-w4.z; aux[1][l]=w4.y-w4.w; aux[2][l]=bg[l]; aux[3][l]=lnkg[l];
    }
    __syncthreads();
    if(tid<64){ float s=0.f; for(int d=0;d<64;d++) s+=lnqb[d]*M0[tid][d]; vtmp[0][tid]=0.125f*s; } // qb
    else if(tid<128){ int c2=tid-64; float s=bm[c2]; for(int d=0;d<64;d++) s+=lnkb[d]*M1[c2][d]; vtmp[1][c2]=s; } // bm2
    else if(tid<192){ int o=tid-128; float s=0.f; for(int d=0;d<64;d++) s+=lnfb[d]*wk[o*64+d]; vtmp[2][o]=s; } // fkb
    __syncthreads();
    // M2T[e][d] = P[d][e] = 0.125*lnqg[d]*sum_c wq[c,d]*wm[c,e]   (4x4 blocked)
    {
      int d0=(tid>>4)*4, e0=(tid&15)*4;
      float acc[4][4]={};
      for(int c2=0;c2<64;c2++) MM44(&M0[c2][d0], &M1[c2][e0]);
      float lq4[4]; *(float4*)lq4 = *(const float4*)(lnqg+d0);
      #pragma unroll
      for(int jj=0;jj<4;jj++){
        float w4[4];
        #pragma unroll
        for(int ii=0;ii<4;ii++) w4[ii]=0.125f*lq4[ii]*acc[ii][jj];
        *(float4*)&M2T[e0+jj][d0] = *(float4*)w4;
      }
    }
    __syncthreads();
    if(tid<64){ // vtmp3[e] = sum_c qb[c]*wm[c,e]
      int e=tid; float s=0.f; for(int c2=0;c2<64;c2++) s=fmaf(vtmp[0][c2], M1[c2][e], s); vtmp[3][e]=s;
    } else if(tid<128){ // v4[d] = 0.125*lnqg[d]*sum_c wq[c,d]*bm2[c]
      int d=tid-64; float s=0.f; for(int c2=0;c2<64;c2++) s=fmaf(M0[c2][d], vtmp[1][c2], s);
      vqp[4*64+d]=0.125f*lnqg[d]*s;
    }
    __syncthreads();
    // overwrite M0 with wkL[e][o] = lnkg[e]*wk[e,o]
    for(int i=tid;i<4096;i+=256){ int e=i>>6,o=i&63; M0[e][o]=aux[3][e]*wk[i]; }
    __syncthreads();
    // WQ[d][o] = lnfg[o]*sum_e M2T[e][d]*wkL[e][o]
    {
      int d0=(tid>>4)*4, o0=(tid&15)*4;
      float acc[4][4]={};
      for(int e=0;e<64;e++) MM44(&M2T[e][d0], &M0[e][o0]);
      float lf4[4]; *(float4*)lf4 = *(const float4*)(lnfg+o0);
      #pragma unroll
      for(int ii=0;ii<4;ii++){
        float w4[4];
        #pragma unroll
        for(int jj=0;jj<4;jj++) w4[jj]=lf4[jj]*acc[ii][jj];
        *(float4*)(WQp + (d0+ii)*64 + o0) = *(float4*)w4;
      }
    }
    // finishers: all LDS-resident
    if(tid<64){ int o=tid; float s=0.f;
      for(int e=0;e<64;e++) s=fmaf(vtmp[3][e], M0[e][o], s);
      bq2p[o]=lnfg[o]*s; }
    else if(tid<128){ int d=tid-64; float s1=0.f,sx=0.f,sy=0.f,s3=0.f;
      for(int e=0;e<64;e++){ float pe=M2T[e][d]*aux[3][e];
        s1+=pe; sx+=pe*aux[0][e]; sy+=pe*aux[1][e]; s3+=pe*(aux[2][e]+vtmp[2][e]); }
      vqp[0*64+d]=s1; vqp[1*64+d]=sx; vqp[2*64+d]=sy; vqp[3*64+d]=s3; }
    else if(tid<192){ // wave-parallel csc (wave 2, lane e)
      int e=tid-128;
      float qe=vtmp[3][e]*aux[3][e];
      float c0=wsum64(qe);
      float c1=wsum64(qe*aux[0][e]);
      float c2=wsum64(qe*aux[1][e]);
      float c3=wsum64(qe*(aux[2][e]+vtmp[2][e]));
      float c4=wsum64(vtmp[0][e]*vtmp[1][e]);
      if(e==0){ cscp[0]=c0; cscp[1]=c1; cscp[2]=c2; cscp[3]=c3; cscp[4]=c4; }
    }
  } else {
    // gru-side collapse: WC[d][o] = lnfg[d]*sum_e wv[e,d]*lnkg[e]*wm[o,e]
    for(int i=tid;i<4096;i+=256){ int r=i>>6,c2=i&63; M0[r][c2]=wv[i]*lnkg[r]; M1[c2][r]=wm[i]; }
    if(tid>=192){ int l=tid-192;
      float4 w4 = *(const float4*)(wg + l*4);
      aux[0][l]=w4.x-w4.z; aux[1][l]=w4.y-w4.w; aux[2][l]=bg[l]; aux[3][l]=lnkg[l];
    }
    __syncthreads();
    if(tid<64){ float s=0.f; const float* wr=wv+tid*64;
      for(int d=0;d<64;d++) s+=lnfb[d]*wr[d]; vtmp[0][tid]=s; } // fvb
    __syncthreads();
    {
      int d0=(tid>>4)*4, o0=(tid&15)*4;
      float acc[4][4]={};
      for(int e=0;e<64;e++) MM44(&M0[e][d0], &M1[e][o0]);
      float lf4[4]; *(float4*)lf4 = *(const float4*)(lnfg+d0);
      #pragma unroll
      for(int ii=0;ii<4;ii++){
        float w4[4];
        #pragma unroll
        for(int jj=0;jj<4;jj++) w4[jj]=lf4[ii]*acc[ii][jj];
        *(float4*)(WCp + (d0+ii)*64 + o0) = *(float4*)w4;
      }
    }
    if(tid<64){ int o=tid; float s1=0.f,s2=0.f,s3=0.f,s4=0.f;
      for(int e=0;e<64;e++){ float we=aux[3][e]*M1[e][o];
        s1+=we*(vtmp[0][e]+aux[2][e]); s2+=we*aux[0][e]; s3+=we*aux[1][e]; s4+=we; }
      uvp[0*64+o]=s1; uvp[1*64+o]=s2; uvp[2*64+o]=s3; uvp[3*64+o]=s4; }
  }
  #undef MM44
}

// feat LN -> A (bf16); transient MFMA fk/fv rows -> per-row stat float4s; color LN.
__global__ __launch_bounds__(256) void k_featln(const float* __restrict__ feat,
    const float* __restrict__ wk, const float* __restrict__ wv, const float* __restrict__ gf,
    const float* __restrict__ fkb, const float* __restrict__ fvb,
    const float* __restrict__ wgx, const float* __restrict__ wgy, const float* __restrict__ bg,
    const float* __restrict__ fc, const float* __restrict__ gc, const float* __restrict__ bc,
    uint16_t* __restrict__ Aout, float4* __restrict__ kstat, float4* __restrict__ vstat,
    float* __restrict__ fcn){
  int tid=threadIdx.x, wid=tid>>6, lane=tid&63;
  int q=lane>>4, c=lane&15;
  size_t row = (size_t)blockIdx.x*64 + wid*16 + c;
  const float* xp = feat + row*64;
  float x[16];
  *(float4*)&x[0]  = *(const float4*)(xp + q*8);
  *(float4*)&x[4]  = *(const float4*)(xp + q*8 + 4);
  *(float4*)&x[8]  = *(const float4*)(xp + 32 + q*8);
  *(float4*)&x[12] = *(const float4*)(xp + 36 + q*8);
  float s=0.f;
  #pragma unroll
  for(int i=0;i<16;i++) s+=x[i];
  s += __shfl_xor(s,16,64); s += __shfl_xor(s,32,64);
  float mean = s*(1.f/64.f);
  float v=0.f;
  #pragma unroll
  for(int i=0;i<16;i++){ float d=x[i]-mean; v+=d*d; }
  v += __shfl_xor(v,16,64); v += __shfl_xor(v,32,64);
  float rs = rsqrtf(v*(1.f/64.f)+EPS);
  float gl[16];
  *(float4*)&gl[0]  = *(const float4*)(gf + q*8);
  *(float4*)&gl[4]  = *(const float4*)(gf + q*8 + 4);
  *(float4*)&gl[8]  = *(const float4*)(gf + 32 + q*8);
  *(float4*)&gl[12] = *(const float4*)(gf + 36 + q*8);
  bf16x8 A0, A1;
  #pragma unroll
  for(int j=0;j<8;j++){
    A0[j] = (short)f2bf((x[j]  -mean)*rs);
    A1[j] = (short)f2bf((x[8+j]-mean)*rs);
  }
  *(bf16x8*)(Aout + row*64 + q*8) = A0;
  *(bf16x8*)(Aout + row*64 + 32 + q*8) = A1;
  float wgxl[4][4], wgyl[4][4], bgl[4][4];
  #pragma unroll
  for(int ot=0;ot<4;ot++){
    *(float4*)&wgxl[ot][0] = *(const float4*)(wgx + ot*16 + q*4);
    *(float4*)&wgyl[ot][0] = *(const float4*)(wgy + ot*16 + q*4);
    *(float4*)&bgl[ot][0]  = *(const float4*)(bg + ot*16 + q*4);
  }
  #pragma unroll
  for(int mat=0;mat<2;mat++){
    const float* w = mat? wv : wk;
    const float* fb = mat? fvb : fkb;
    float ss=0.f, s2=0.f, dx=0.f, dy=0.f, db=0.f;
    #pragma unroll
    for(int ot=0; ot<4; ot++){
      const float* wp = w + (size_t)(ot*16+c)*64 + q*8;
      bf16x8 W0, W1;
      #pragma unroll
      for(int j=0;j<8;j++){ W0[j]=(short)f2bf(wp[j]*gl[j]); W1[j]=(short)f2bf(wp[32+j]*gl[8+j]); }
      float4 bq = *(const float4*)(fb + ot*16 + q*4);
      f32x4 acc = {bq.x,bq.y,bq.z,bq.w};
      acc = __builtin_amdgcn_mfma_f32_16x16x32_bf16(W0, A0, acc, 0,0,0);
      acc = __builtin_amdgcn_mfma_f32_16x16x32_bf16(W1, A1, acc, 0,0,0);
      #pragma unroll
      for(int r=0;r<4;r++){
        float a=acc[r];
        ss+=a; s2+=a*a;
        dx = fmaf(a, wgxl[ot][r], dx);
        dy = fmaf(a, wgyl[ot][r], dy);
        db = fmaf(a, bgl[ot][r], db);
      }
    }
    ss += __shfl_xor(ss,16,64); ss += __shfl_xor(ss,32,64);
    s2 += __shfl_xor(s2,16,64); s2 += __shfl_xor(s2,32,64);
    dx += __shfl_xor(dx,16,64); dx += __shfl_xor(dx,32,64);
    dy += __shfl_xor(dy,16,64); dy += __shfl_xor(dy,32,64);
    db += __shfl_xor(db,16,64); db += __shfl_xor(db,32,64);
    if(lane<16){
      size_t row2 = (size_t)blockIdx.x*64 + wid*16 + lane;
      float4 st = { ss*(1.f/64.f), s2*(1.f/64.f)+db*(1.f/32.f), dx*(1.f/32.f), dy*(1.f/32.f) };
      (mat? vstat : kstat)[row2] = st;
    }
  }
  int r16=tid>>4, cc=tid&15;
  #pragma unroll
  for(int i=0;i<4;i++){
    size_t row2 = (size_t)blockIdx.x*64 + i*16 + r16;
    float xv = fc[row2*16+cc];
    float sc=xv;
    #pragma unroll
    for(int o=1;o<16;o<<=1) sc += __shfl_xor(sc,o,16);
    float m2 = sc*(1.f/16.f);
    float df = xv-m2;
    float v2 = df*df;
    #pragma unroll
    for(int o=1;o<16;o<<=1) v2 += __shfl_xor(v2,o,16);
    fcn[row2*16+cc] = df*rsqrtf(v2*(1.f/16.f)+EPS)*gc[cc] + bc[cc];
  }
}

// Block-parallel per-bk preamble: collapsed GRU merge + single-matvec q chain.
// 80 blocks x 256 threads. NC_=64 chunk merge is full-wave lane-parallel.
template<bool GRU>
__global__ __launch_bounds__(256) void k_slotq(
    const float* __restrict__ slot_prev, float* __restrict__ slot_cur,
    const float* __restrict__ part, const float* __restrict__ pscal,
    const float* __restrict__ red_in,
    const float* __restrict__ gw,
    const float* __restrict__ bih, const float* __restrict__ bhh,
    const float* __restrict__ wrpT, const float* __restrict__ br2,
    const float* __restrict__ bm2,
    const float* __restrict__ WQ, const float* __restrict__ bq2,
    const float* __restrict__ WC, const float* __restrict__ uvec,
    const float* __restrict__ vq, const float* __restrict__ csc,
    const float* __restrict__ gscal,
    float* __restrict__ qs_out, float* __restrict__ cst_out){
  __shared__ float vv[64], vh[64];
  __shared__ float red6[4][64][6];
  __shared__ float lamb[NC_];
  __shared__ float sc4[4];
  int bk=blockIdx.x;
  int tid=threadIdx.x, wid=tid>>6, lane=tid&63;
  int o=lane, qq=wid;
  float mwgx=gscal[0], mwgy=gscal[1], mbg=gscal[2];

  #define MV(Wptr) { float p_=0.f; \
      _Pragma("unroll") \
      for(int dd=0;dd<16;dd++) p_ = fmaf(vv[qq*16+dd], (Wptr)[(qq*16+dd)*64+o], p_); \
      red6[qq][o][0]=p_; } __syncthreads();
  #define SUM0 (red6[0][lane][0]+red6[1][lane][0]+red6[2][lane][0]+red6[3][lane][0])

  float cur=0.f, hp=0.f;
  if(GRU){
    if(wid==0){
      // lane-parallel chunk merge (NC_=64 -> all lanes)
      float m_l = red_in[((size_t)bk*NC_+lane)*4];
      float s_l = red_in[((size_t)bk*NC_+lane)*4+1];
      float M = wmax64(m_l);
      float eu = __expf(m_l-M);
      float S = wsum64(s_l*eu);
      float lam = eu/S;
      lamb[lane]=lam;
      float p0 = pscal[((size_t)bk*NC_+lane)*4+0];
      float p1 = pscal[((size_t)bk*NC_+lane)*4+1];
      float p2 = pscal[((size_t)bk*NC_+lane)*4+2];
      float p3 = pscal[((size_t)bk*NC_+lane)*4+3];
      float As = wsum64(lam*p0), Ax = wsum64(lam*p1);
      float Ay = wsum64(lam*p2), Am = wsum64(lam*p3);
      if(lane==0){ sc4[0]=As; sc4[1]=Ax; sc4[2]=Ay; sc4[3]=Am; }
    }
    __syncthreads();
    { // sA partials: wave qq handles chunks qq*16..qq*16+15
      float p_=0.f;
      #pragma unroll
      for(int j=0;j<16;j++){
        int cc = qq*16+j;
        p_ = fmaf(lamb[cc], part[((size_t)bk*NC_+cc)*64+o], p_);
      }
      red6[qq][o][0]=p_;
    }
    __syncthreads();
    if(wid==0) vv[lane] = SUM0;        // sA (WC absorbs lnfg)
    __syncthreads();
    MV(WC);
    if(wid==0){
      float As=sc4[0],Ax=sc4[1],Ay=sc4[2],Am=sc4[3];
      float x_ = SUM0 + As*uvec[lane] + Ax*uvec[64+lane] + Ay*uvec[128+lane]
               - Am*uvec[192+lane] + bm2[lane];
      hp = slot_prev[bk*64+lane];
      vv[lane]=x_; vh[lane]=hp;
    }
    __syncthreads();
    {
      float p0=0.f,p1=0.f,p2=0.f,p3=0.f,p4=0.f,p5=0.f;
      #pragma unroll
      for(int dd=0;dd<16;dd++){
        int d = qq*16+dd;
        float xd=vv[d], hd=vh[d];
        p0 = fmaf(xd, gw[d*64+o], p0);
        p1 = fmaf(xd, gw[4096+d*64+o], p1);
        p2 = fmaf(xd, gw[8192+d*64+o], p2);
        p3 = fmaf(hd, gw[12288+d*64+o], p3);
        p4 = fmaf(hd, gw[16384+d*64+o], p4);
        p5 = fmaf(hd, gw[20480+d*64+o], p5);
      }
      red6[qq][o][0]=p0; red6[qq][o][1]=p1; red6[qq][o][2]=p2;
      red6[qq][o][3]=p3; red6[qq][o][4]=p4; red6[qq][o][5]=p5;
    }
    __syncthreads();
    if(wid==0){
      float gir=bih[lane], giz=bih[64+lane], gin=bih[128+lane];
      float ghr=bhh[lane], ghz=bhh[64+lane], ghn=bhh[128+lane];
      #pragma unroll
      for(int w=0;w<4;w++){
        gir+=red6[w][lane][0]; giz+=red6[w][lane][1]; gin+=red6[w][lane][2];
        ghr+=red6[w][lane][3]; ghz+=red6[w][lane][4]; ghn+=red6[w][lane][5];
      }
      float r=1.f/(1.f+__expf(-(gir+ghr)));
      float z=1.f/(1.f+__expf(-(giz+ghz)));
      float nn=tanhf(gin+r*ghn);
      float sp=(1.f-z)*nn+z*hp;
      float m=wsum64(sp)*(1.f/64.f); float df=sp-m;
      float var=wsum64(df*df)*(1.f/64.f);
      vv[lane]=df*rsqrtf(var+EPS);
    }
    __syncthreads();
    MV(wrpT);
    if(wid==0){
      cur = SUM0 + br2[lane] + hp;
      slot_cur[bk*64+lane]=cur;
    }
  } else {
    if(wid==0) cur = slot_prev[bk*64+lane];
  }
  __syncthreads();
  if(wid==0){
    float m=wsum64(cur)*(1.f/64.f); float df=cur-m;
    float var=wsum64(df*df)*(1.f/64.f);
    float LNc=df*rsqrtf(var+EPS);
    vv[lane]=LNc;
    float s1=wsum64(LNc*vq[lane])     + csc[0];
    float c1=wsum64(LNc*vq[64+lane])  + csc[1];
    float c2=wsum64(LNc*vq[128+lane]) + csc[2];
    float c3=wsum64(LNc*vq[192+lane]) + csc[3];
    float c4=wsum64(LNc*vq[256+lane]) + csc[4];
    if(lane==0){
      float* cp = cst_out + bk*8;
      cp[0]=c1-s1*mwgx; cp[1]=c2-s1*mwgy; cp[2]=c3-s1*mbg; cp[3]=s1; cp[4]=c4;
    }
  }
  __syncthreads();
  MV(WQ);
  if(wid==0) qs_out[bk*64+lane] = SUM0 + bq2[lane];
  #undef MV
  #undef SUM0
}

// Slot-amortized attention: block = (chunk CS_=64, b), all K=5 slots.
// One chunk = one wave's lanes; phase 2 is single-pass, wave-owned slots:
// wave0 -> slots {0,4}, wave1 -> {1}, wave2 -> {2}, wave3 -> {3}.
// Grid (NC_=64, B_) = 1024 blocks -> 4 blocks/CU.
template<bool FINAL>
__global__ __launch_bounds__(256) void k_attn(const uint16_t* __restrict__ Aw,
    const float4* __restrict__ kstat, const float4* __restrict__ vstat,
    const float* __restrict__ qsg, const float* __restrict__ cstg,
    const float* __restrict__ gscal, const float* __restrict__ ws_fg,
    float* __restrict__ lgt, float* __restrict__ red_out,
    float* __restrict__ part_o, float* __restrict__ pscal_o){
  __shared__ uint32_t As_[CS_*32];      // 8KB: 64 rows x 64 bf16
  __shared__ __align__(16) float dps[5][CS_+4];  // dots -> weights
  __shared__ float pw[4][5][64];
  __shared__ float rm[5], rn[5];
  __shared__ float rsc[5][5];
  __shared__ float cstl[5][5];
  __shared__ float fgl[5][2];
  int chunk=blockIdx.x, b=blockIdx.y;
  int tid=threadIdx.x, wid=tid>>6, lane=tid&63;
  int c=lane&15, q=lane>>4;
  float mwgx=gscal[0], mwgy=gscal[1], mbg=gscal[2];
  float g1=gscal[3], g2=gscal[4], g3=gscal[5], g4=gscal[6], g5=gscal[7], g6=gscal[8];

  // stage A chunk -> LDS (only needed for accumulation; dead in FINAL)
  if(!FINAL){
    const uint4* Ag = (const uint4*)(Aw + ((size_t)b*N_ + chunk*CS_)*64);
    #pragma unroll
    for(int jj=0;jj<2;jj++){
      int f = jj*256 + tid;
      *(uint4*)(As_ + f*4) = Ag[f];
    }
  }
  if(tid<25) cstl[tid/5][tid%5] = cstg[(b*K_ + tid/5)*8 + (tid%5)];
  if(tid>=32 && tid<42){ int i2=tid-32; fgl[i2>>1][i2&1] = ws_fg[i2]; }
  // row = lane (all waves see the same 64 rows; slots are wave-owned)
  int nrow = chunk*CS_ + lane;
  float4 st = kstat[(size_t)b*N_ + nrow];
  float4 sv;
  if(!FINAL) sv = vstat[(size_t)b*N_ + nrow];
  float gx = -1.f + (2.f/63.f)*(nrow&63);
  float gy = -1.f + (2.f/63.f)*(nrow>>6);
  __syncthreads();

  // phase 1: MFMA dots; one 16-row tile per wave
  {
    bf16x8 QF0={0,0,0,0,0,0,0,0}, QF1={0,0,0,0,0,0,0,0};
    if(c<5){
      const float* qpp = qsg + (b*K_+c)*64;
      #pragma unroll
      for(int j=0;j<8;j++){
        QF0[j] = (short)f2bf(qpp[q*8+j]);
        QF1[j] = (short)f2bf(qpp[32+q*8+j]);
      }
    }
    const uint16_t* Abase = Aw + ((size_t)b*N_ + chunk*CS_)*64;
    int tile = wid*16;
    const uint16_t* rp = Abase + (size_t)(tile+c)*64;
    bf16x8 BF0 = *(const bf16x8*)(rp + q*8);
    bf16x8 BF1 = *(const bf16x8*)(rp + 32 + q*8);
    f32x4 acc = {0.f,0.f,0.f,0.f};
    acc = __builtin_amdgcn_mfma_f32_16x16x32_bf16(QF0, BF0, acc, 0,0,0);
    acc = __builtin_amdgcn_mfma_f32_16x16x32_bf16(QF1, BF1, acc, 0,0,0);
    #pragma unroll
    for(int r=0;r<4;r++){
      int s = q*4+r;
      if(s<5) dps[s][tile+c]=acc[r];
    }
  }
  __syncthreads();

  // phase 2: single pass; wave-owned slots; chunk max = one wmax64
  int nsl = (wid==0)? 2 : 1;
  #pragma unroll
  for(int j=0;j<2;j++){
    if(j<nsl){
      int k = (j==0)? wid : 4;
      float rx = gx - fgl[k][0], ry = gy - fgl[k][1];
      float CX=cstl[k][0], CY=cstl[k][1], C0=cstl[k][2], S1=cstl[k][3], C4=cstl[k][4];
      float quad = g1*rx*rx + g2*ry*ry + g3*rx*ry + g4*rx + g5*ry + g6;
      float mu = st.x + rx*mwgx + ry*mwgy + mbg;
      float var = st.y + rx*st.z + ry*st.w + quad - mu*mu;
      float rsn = rsqrtf(var+EPS);
      float l = rsn*(dps[k][lane] + rx*CX + ry*CY + C0 - S1*st.x) + C4;
      float m_c = wmax64(l);
      float e = __expf(l-m_c);
      float scq = wsum64(e);
      if(!FINAL){
        float muV = sv.x + rx*mwgx + ry*mwgy + mbg;
        float varV = sv.y + rx*sv.z + ry*sv.w + quad - muV*muV;
        float rsv_ = rsqrtf(varV+EPS);
        float w_ = e*rsv_;
        float As2=wsum64(w_), Ax2=wsum64(w_*rx), Ay2=wsum64(w_*ry), Am2=wsum64(w_*muV);
        if(lane==0){ rm[k]=m_c; rsc[k][0]=scq; rsc[k][1]=As2; rsc[k][2]=Ax2;
                     rsc[k][3]=Ay2; rsc[k][4]=Am2; }
        dps[k][lane] = w_;          // wave-exclusive overwrite dot -> weight
      } else {
        float mn = wmin64(l);
        lgt[(size_t)(b*K_+k)*N_ + nrow] = l;
        if(lane==0){ rm[k]=m_c; rn[k]=mn; rsc[k][0]=scq; }
      }
    }
  }
  __syncthreads();
  if(tid<5){
    int k=tid;
    size_t idx = ((size_t)(b*K_+k)*NC_+chunk)*4;
    red_out[idx+0]=rm[k];
    red_out[idx+1]=rsc[k][0];
    if(FINAL) red_out[idx+2]=rn[k];
    if(!FINAL){
      pscal_o[idx+0]=rsc[k][1];
      pscal_o[idx+1]=rsc[k][2];
      pscal_o[idx+2]=rsc[k][3];
      pscal_o[idx+3]=rsc[k][4];
    }
  }

  // accumulation: part[k][ch] = sum_row w_k[row]*A[row][ch]; wave wid rows wid*16..+15
  if(!FINAL){
    const uint16_t* Au = (const uint16_t*)As_;
    float a0=0.f,a1=0.f,a2=0.f,a3=0.f,a4=0.f;
    #pragma unroll
    for(int rb=0;rb<4;rb++){
      int row0 = wid*16 + rb*4;
      float4 d0 = *(const float4*)&dps[0][row0];
      float4 d1 = *(const float4*)&dps[1][row0];
      float4 d2 = *(const float4*)&dps[2][row0];
      float4 d3 = *(const float4*)&dps[3][row0];
      float4 d4 = *(const float4*)&dps[4][row0];
      float av0 = __uint_as_float(((uint32_t)Au[(row0+0)*64+lane])<<16);
      float av1 = __uint_as_float(((uint32_t)Au[(row0+1)*64+lane])<<16);
      float av2 = __uint_as_float(((uint32_t)Au[(row0+2)*64+lane])<<16);
      float av3 = __uint_as_float(((uint32_t)Au[(row0+3)*64+lane])<<16);
      a0=fmaf(d0.x,av0,a0); a0=fmaf(d0.y,av1,a0); a0=fmaf(d0.z,av2,a0); a0=fmaf(d0.w,av3,a0);
      a1=fmaf(d1.x,av0,a1); a1=fmaf(d1.y,av1,a1); a1=fmaf(d1.z,av2,a1); a1=fmaf(d1.w,av3,a1);
      a2=fmaf(d2.x,av0,a2); a2=fmaf(d2.y,av1,a2); a2=fmaf(d2.z,av2,a2); a2=fmaf(d2.w,av3,a2);
      a3=fmaf(d3.x,av0,a3); a3=fmaf(d3.y,av1,a3); a3=fmaf(d3.z,av2,a3); a3=fmaf(d3.w,av3,a3);
      a4=fmaf(d4.x,av0,a4); a4=fmaf(d4.y,av1,a4); a4=fmaf(d4.z,av2,a4); a4=fmaf(d4.w,av3,a4);
    }
    pw[wid][0][lane]=a0; pw[wid][1][lane]=a1; pw[wid][2][lane]=a2;
    pw[wid][3][lane]=a3; pw[wid][4][lane]=a4;
    __syncthreads();
    if(tid<64){
      #pragma unroll
      for(int k=0;k<5;k++){
        float s2 = pw[0][k][tid]+pw[1][k][tid]+pw[2][k][tid]+pw[3][k][tid];
        part_o[((size_t)(b*K_+k)*NC_+chunk)*64 + tid] = s2;
      }
    }
  }
}

// fin: p from global stats; out_attn; color partial atomicAdd; slot write (chunk 0)
__global__ __launch_bounds__(256) void k_fin(const float* __restrict__ lgt,
    const float* __restrict__ red, const float* __restrict__ featc,
    const float* __restrict__ sl1, float* __restrict__ out_slot,
    float* __restrict__ out_attn){
  __shared__ float psp[CS_];
  __shared__ float pcz[4][16];
  int chunk=blockIdx.x, bk=blockIdx.y, b=bk/K_;
  int tid=threadIdx.x, wid=tid>>6, lane=tid&63, sub=lane>>4, c4=lane&15;
  const float4* rp4 = (const float4*)(red + (size_t)bk*NC_*4);
  float M=-1e30f;
  #pragma unroll
  for(int i=0;i<NC_;i++) M = fmaxf(M, rp4[i].x);
  float S=0.f, LMIN=1e30f;
  #pragma unroll
  for(int i=0;i<NC_;i++){ float4 r4=rp4[i]; S += r4.y*__expf(r4.x-M); LMIN=fminf(LMIN, r4.z); }
  float invS = 1.f/S;
  float amin = __expf(LMIN-M)*invS;
  float dinv = 1.f/(invS - amin + 1e-5f);
  const float* lp = lgt + (size_t)bk*N_ + chunk*CS_;
  if(tid<CS_){
    float p = __expf(lp[tid]-M)*invS;
    psp[tid]=p;
    out_attn[(size_t)bk*N_ + chunk*CS_ + tid] = (p - amin)*dinv;
  }
  __syncthreads();
  const float* Fb = featc + ((size_t)b*N_ + chunk*CS_)*16;
  float ac=0.f;
  #pragma unroll
  for(int t=0;t<4;t++){
    int n = wid*16 + t*4 + sub;
    ac += psp[n]*Fb[(size_t)n*16 + c4];
  }
  ac+=__shfl_xor(ac,16,64); ac+=__shfl_xor(ac,32,64);
  if(lane<16) pcz[wid][lane]=ac;
  __syncthreads();
  if(tid<16){
    float s2 = pcz[0][tid]+pcz[1][tid]+pcz[2][tid]+pcz[3][tid];
    atomicAdd(&out_slot[bk*80+64+tid], s2);
  }
  if(chunk==0 && tid<64) out_slot[bk*80+tid]=sl1[bk*64+tid];
}

extern "C" void kernel_launch(void* const* d_in, const int* in_sizes, int n_in,
                              void* d_out, int out_size, void* d_ws, size_t ws_size,
                              hipStream_t stream){
  (void)in_sizes; (void)n_in; (void)out_size; (void)ws_size;
  const float* feat = (const float*)d_in[0];
  const float* featc= (const float*)d_in[1];
  const float* mask = (const float*)d_in[2];
  const float* noise= (const float*)d_in[3];
  const float* mu   = (const float*)d_in[4];
  const float* lsg  = (const float*)d_in[5];
  const float* wg   = (const float*)d_in[6];
  const float* bg   = (const float*)d_in[7];
  const float* wk   = (const float*)d_in[8];
  const float* wv   = (const float*)d_in[9];
  const float* lnkg = (const float*)d_in[10];
  const float* lnkb = (const float*)d_in[11];
  const float* wm   = (const float*)d_in[12];
  const float* bm   = (const float*)d_in[13];
  const float* lnqg = (const float*)d_in[14];
  const float* lnqb = (const float*)d_in[15];
  const float* wq   = (const float*)d_in[16];
  const float* wih  = (const float*)d_in[17];
  const float* whh  = (const float*)d_in[18];
  const float* bih  = (const float*)d_in[19];
  const float* bhh  = (const float*)d_in[20];
  const float* lnfg = (const float*)d_in[21];
  const float* lnfb = (const float*)d_in[22];
  const float* lncg = (const float*)d_in[23];
  const float* lncb = (const float*)d_in[24];
  const float* lnrg = (const float*)d_in[25];
  const float* lnrb = (const float*)d_in[26];
  const float* wres = (const float*)d_in[27];
  const float* bres = (const float*)d_in[28];

  float* out = (float*)d_out;
  float* out_slot = out;          // (B,K,80)
  float* out_fg   = out + 6400;   // (B,K,2)
  float* out_attn = out + 6560;   // (B,K,N)

  float* wsf     = (float*)d_ws;
  float* ws_fg   = wsf;                                // 16
  float* ws_bm2  = wsf + 16;                           // 64
  float* ws_fkb  = ws_bm2 + 64;                        // 64
  float* ws_fvb  = ws_fkb + 64;                        // 64
  float* ws_qb   = ws_fvb + 64;                        // 64
  float* ws_br2  = ws_qb + 64;                         // 64
  float* ws_wgx  = ws_br2 + 64;                        // 64
  float* ws_wgy  = ws_wgx + 64;                        // 64
  float* ws_gs   = ws_wgy + 64;                        // 16
  float* ws_wrpT = ws_gs + 16;                         // 4096
  float* ws_gw   = ws_wrpT + 4096;                     // 24576
  float* ws_WQ   = ws_gw + 24576;                      // 4096
  float* ws_WC   = ws_WQ + 4096;                       // 4096
  float* ws_bq2  = ws_WC + 4096;                       // 64
  float* ws_u    = ws_bq2 + 64;                        // 256
  float* ws_vq   = ws_u + 256;                         // 320
  float* ws_csc  = ws_vq + 320;                        // 16
  float* ws_qs   = ws_csc + 16;                        // 5120
  float* ws_cst  = ws_qs + B_*K_*D_;                   // 640
  float* ws_fc   = ws_cst + 640;                       // B*N*C
  float* ws_sl0  = ws_fc + (size_t)B_*N_*C_;           // 5120
  float* ws_sl1  = ws_sl0 + B_*K_*D_;                  // 5120
  float* ws_lgt  = ws_sl1 + B_*K_*D_;                  // B*K*N
  float* ws_red0 = ws_lgt + (size_t)B_*K_*N_;          // 80*NC*4
  float* ws_red1 = ws_red0 + B_*K_*NC_*4;              // 80*NC*4
  float* ws_prt0 = ws_red1 + B_*K_*NC_*4;              // 80*NC*64
  float* ws_prt1 = ws_prt0 + (size_t)B_*K_*NC_*64;     // 80*NC*64
  float* ws_psc0 = ws_prt1 + (size_t)B_*K_*NC_*64;     // 80*NC*4
  float* ws_psc1 = ws_psc0 + B_*K_*NC_*4;              // 80*NC*4
  float4* ws_kst = (float4*)(ws_psc1 + B_*K_*NC_*4);   // B*N float4
  float4* ws_vst = ws_kst + (size_t)B_*N_;             // B*N float4
  uint16_t* ws_A = (uint16_t*)(ws_vst + (size_t)B_*N_);// B*N*64 bf16

  k_pre<<<141,256,0,stream>>>(mask,noise,mu,lsg, wm,bm,lnkb, wk,wv,lnfb,
                              wq,lnqg,lnqb, wres,bres,lnrg,lnrb, wih,whh, wg,bg,
                              lnfg,lnkg,
                              ws_fg,out_fg, ws_bm2,ws_fkb,ws_fvb,ws_qb,ws_br2,
                              ws_wgx,ws_wgy,ws_gs,
                              ws_wrpT, ws_gw, ws_sl0, out_slot,
                              ws_WQ, ws_WC, ws_bq2, ws_u, ws_vq, ws_csc);
  k_featln<<<(B_*N_)/64,256,0,stream>>>(feat,wk,wv,lnfg,ws_fkb,ws_fvb,
                                        ws_wgx,ws_wgy,bg,
                                        featc,lncg,lncb,
                                        ws_A,ws_kst,ws_vst,ws_fc);

  dim3 agrid(NC_,B_);
  #define SQ_ARGS(SPREV,SCUR,PIN,SCIN,RIN) SPREV,SCUR,PIN,SCIN,RIN,ws_gw, \
      bih,bhh,ws_wrpT,ws_br2,ws_bm2, ws_WQ,ws_bq2, ws_WC,ws_u, ws_vq,ws_csc, \
      ws_gs, ws_qs,ws_cst
  #define AT_ARGS(ROUT,POUT,SCOUT) ws_A,ws_kst,ws_vst,ws_qs,ws_cst,ws_gs,ws_fg, \
      ws_lgt,ROUT,POUT,SCOUT

  k_slotq<false><<<B_*K_,256,0,stream>>>(SQ_ARGS(ws_sl0,ws_sl0,ws_prt1,ws_psc1,ws_red1));
  k_attn<false><<<agrid,256,0,stream>>>(AT_ARGS(ws_red0,ws_prt0,ws_psc0));
  k_slotq<true><<<B_*K_,256,0,stream>>>(SQ_ARGS(ws_sl0,ws_sl1,ws_prt0,ws_psc0,ws_red0));
  k_attn<false><<<agrid,256,0,stream>>>(AT_ARGS(ws_red1,ws_prt1,ws_psc1));
  k_slotq<true><<<B_*K_,256,0,stream>>>(SQ_ARGS(ws_sl1,ws_sl0,ws_prt1,ws_psc1,ws_red1));
  k_attn<false><<<agrid,256,0,stream>>>(AT_ARGS(ws_red0,ws_prt0,ws_psc0));
  k_slotq<true><<<B_*K_,256,0,stream>>>(SQ_ARGS(ws_sl0,ws_sl1,ws_prt0,ws_psc0,ws_red0));
  k_attn<true><<<agrid,256,0,stream>>>(AT_ARGS(ws_red1,ws_prt1,ws_psc1));
  k_fin<<<dim3(NC_,B_*K_),256,0,stream>>>(ws_lgt,ws_red1,ws_fc,ws_sl1,out_slot,out_attn);
}

// Round 8
// 223.013 us; speedup vs baseline: 1.0154x; 1.0154x over previous
//
#include <hip/hip_runtime.h>
#include <stdint.h>

#define B_ 16
#define H_ 64
#define W_ 64
#define D_ 64
#define C_ 16
#define K_ 5
#define N_ 4096
#define NC_ 32         // attention n-chunks
#define CS_ 128        // chunk size = N_/NC_
#define EPS 1e-5f

typedef __attribute__((ext_vector_type(8))) short bf16x8;
typedef __attribute__((ext_vector_type(4))) float f32x4;

__device__ __forceinline__ float wsum64(float v){
  #pragma unroll
  for(int o=1;o<64;o<<=1) v += __shfl_xor(v,o,64);
  return v;
}
__device__ __forceinline__ float wmax64(float v){
  #pragma unroll
  for(int o=1;o<64;o<<=1) v = fmaxf(v, __shfl_xor(v,o,64));
  return v;
}
__device__ __forceinline__ float wmin64(float v){
  #pragma unroll
  for(int o=1;o<64;o<<=1) v = fminf(v, __shfl_xor(v,o,64));
  return v;
}
__device__ __forceinline__ uint16_t f2bf(float f){
  uint32_t u = __float_as_uint(f);
  u += 0x7fffu + ((u>>16)&1u);
  return (uint16_t)(u>>16);
}

// k_pre: fgpos (0-4) + folded biases (5) + fvb/wgx/wgy/gscal/out_slot-zero (6)
// + wrpT (7-22) + gw (23-118) + slot init (119-138)
// + q-side collapse WQ/bq2/vq/csc (139) + gru-side collapse WC/uvec (140)
// Collapse matmuls 4x4 register-blocked; finishers LDS-staged + wave-parallel.
__global__ __launch_bounds__(256) void k_pre(
    const float* __restrict__ mask, const float* __restrict__ noise,
    const float* __restrict__ mu, const float* __restrict__ lsg,
    const float* __restrict__ wm, const float* __restrict__ bm, const float* __restrict__ lnkb,
    const float* __restrict__ wk, const float* __restrict__ wv, const float* __restrict__ lnfb,
    const float* __restrict__ wq, const float* __restrict__ lnqg, const float* __restrict__ lnqb,
    const float* __restrict__ wres, const float* __restrict__ bres,
    const float* __restrict__ lnrg, const float* __restrict__ lnrb,
    const float* __restrict__ wih, const float* __restrict__ whh,
    const float* __restrict__ wg, const float* __restrict__ bg,
    const float* __restrict__ lnfg, const float* __restrict__ lnkg,
    float* __restrict__ ws_fg, float* __restrict__ out_fg,
    float* __restrict__ bm2, float* __restrict__ fkb, float* __restrict__ fvb,
    float* __restrict__ qb, float* __restrict__ br2,
    float* __restrict__ wgx, float* __restrict__ wgy, float* __restrict__ gscal,
    float* __restrict__ wrpT,
    float* __restrict__ gw, float* __restrict__ slot, float* __restrict__ out_slot,
    float* __restrict__ WQp, float* __restrict__ WCp, float* __restrict__ bq2p,
    float* __restrict__ uvp, float* __restrict__ vqp, float* __restrict__ cscp){
  __shared__ __align__(16) float M0[64][68];
  __shared__ __align__(16) float M1[64][68];
  __shared__ __align__(16) float M2T[64][68];
  __shared__ float vtmp[4][64];
  __shared__ float aux[4][64];   // wgx, wgy, bg, lnkg staged from global
  int bid=blockIdx.x, tid=threadIdx.x;

  #define MM44(SRCA, SRCB) { \
    float a4[4], b4[4]; \
    *(float4*)a4 = *(const float4*)(SRCA); \
    *(float4*)b4 = *(const float4*)(SRCB); \
    _Pragma("unroll") \
    for(int ii=0;ii<4;ii++){ \
      _Pragma("unroll") \
      for(int jj=0;jj<4;jj++) acc[ii][jj]=fmaf(a4[ii],b4[jj],acc[ii][jj]); \
    } }

  if(bid<5){
    int k=bid;
    float sm=0.f, sx=0.f, sy=0.f;
    for(int p=tid; p<H_*W_; p+=256){
      int i=p>>6, j=p&63;
      float m = mask[k*H_*W_ + p];
      float x = -1.f + (2.f/63.f)*j;
      float y = -1.f + (2.f/63.f)*i;
      sm+=m; sx+=m*x; sy+=m*y;
    }
    __shared__ float r0[4], r1[4], r2[4];
    int wid=tid>>6, lane=tid&63;
    sm=wsum64(sm); sx=wsum64(sx); sy=wsum64(sy);
    if(lane==0){ r0[wid]=sm; r1[wid]=sx; r2[wid]=sy; }
    __syncthreads();
    if(tid==0){
      float tm=r0[0]+r0[1]+r0[2]+r0[3];
      float tx=r1[0]+r1[1]+r1[2]+r1[3];
      float ty=r2[0]+r2[1]+r2[2]+r2[3];
      float px = tx/(tm+1e-5f), py = ty/(tm+1e-5f);
      ws_fg[k*2+0]=px; ws_fg[k*2+1]=py;
      for(int b=0;b<B_;b++){ out_fg[(b*K_+k)*2+0]=px; out_fg[(b*K_+k)*2+1]=py; }
    }
  } else if(bid==5){
    int sel=tid>>6, o=tid&63; float s=0.f;
    if(sel==0){ s=bm[o]; for(int d=0;d<64;d++) s+=lnkb[d]*wm[o*64+d]; bm2[o]=s; }
    else if(sel==1){ for(int d=0;d<64;d++) s+=lnqb[d]*wq[o*64+d]; qb[o]=0.125f*s; }
    else if(sel==2){ for(int d=0;d<64;d++) s+=lnrb[d]*wres[o*64+d]; br2[o]=s+bres[o]; }
    else { for(int d=0;d<64;d++) s+=lnfb[d]*wk[o*64+d]; fkb[o]=s; }
  } else if(bid==6){
    int wv4=tid>>6, l=tid&63;
    if(wv4==0){ float s=0.f; for(int d=0;d<64;d++) s+=lnfb[d]*wv[l*64+d]; fvb[l]=s; }
    else if(wv4==1){
      float4 w4 = *(const float4*)(wg + l*4);
      wgx[l]=w4.x-w4.z; wgy[l]=w4.y-w4.w;
    } else if(wv4==2){
      float4 w4 = *(const float4*)(wg + l*4);
      float wx=w4.x-w4.z, wy=w4.y-w4.w, bl=bg[l];
      float t;
      t=wsum64(wx);    if(l==0) gscal[0]=t*(1.f/64.f);
      t=wsum64(wy);    if(l==0) gscal[1]=t*(1.f/64.f);
      t=wsum64(bl);    if(l==0) gscal[2]=t*(1.f/64.f);
      t=wsum64(wx*wx); if(l==0) gscal[3]=t*(1.f/64.f);
      t=wsum64(wy*wy); if(l==0) gscal[4]=t*(1.f/64.f);
      t=wsum64(wx*wy); if(l==0) gscal[5]=t*(2.f/64.f);
      t=wsum64(wx*bl); if(l==0) gscal[6]=t*(2.f/64.f);
      t=wsum64(wy*bl); if(l==0) gscal[7]=t*(2.f/64.f);
      t=wsum64(bl*bl); if(l==0) gscal[8]=t*(1.f/64.f);
    } else {
      for(int j=l;j<B_*K_*16;j+=64){ int bk2=j>>4, cc2=j&15; out_slot[bk2*80+64+cc2]=0.f; }
    }
  } else if(bid<23){
    int i=(bid-7)*256+tid;           // < 4096
    int d=i>>6, o=i&63;
    wrpT[i]=lnrg[d]*wres[o*64+d];
  } else if(bid<119){
    int i=(bid-23)*256+tid;          // < 24576
    int g6=i>>12, r=i&4095, d=r>>6, o=r&63;
    float v = (g6<3)? wih[(g6*64+o)*64+d] : whh[((g6-3)*64+o)*64+d];
    gw[g6*4096 + d*64 + o] = v;
  } else if(bid<139){
    int i=(bid-119)*256+tid;
    if(i<B_*K_*D_){ int d=i&63; slot[i]=mu[d]+expf(lsg[d])*noise[i]; }
  } else if(bid==139){
    // q-side collapse: WQ = (0.125*lnqg ∘ wq^T @ wm) @ (lnkg ∘ wk) ∘ lnfg
    for(int i=tid;i<4096;i+=256){ int r=i>>6,c2=i&63; M0[r][c2]=wq[i]; M1[r][c2]=wm[i]; }
    if(tid>=192){ int l=tid-192;
      float4 w4 = *(const float4*)(wg + l*4);
      aux[0][l]=w4.x-w4.z; aux[1][l]=w4.y-w4.w; aux[2][l]=bg[l]; aux[3][l]=lnkg[l];
    }
    __syncthreads();
    if(tid<64){ float s=0.f; for(int d=0;d<64;d++) s+=lnqb[d]*M0[tid][d]; vtmp[0][tid]=0.125f*s; } // qb
    else if(tid<128){ int c2=tid-64; float s=bm[c2]; for(int d=0;d<64;d++) s+=lnkb[d]*M1[c2][d]; vtmp[1][c2]=s; } // bm2
    else if(tid<192){ int o=tid-128; float s=0.f; for(int d=0;d<64;d++) s+=lnfb[d]*wk[o*64+d]; vtmp[2][o]=s; } // fkb
    __syncthreads();
    // M2T[e][d] = P[d][e] = 0.125*lnqg[d]*sum_c wq[c,d]*wm[c,e]   (4x4 blocked)
    {
      int d0=(tid>>4)*4, e0=(tid&15)*4;
      float acc[4][4]={};
      for(int c2=0;c2<64;c2++) MM44(&M0[c2][d0], &M1[c2][e0]);
      float lq4[4]; *(float4*)lq4 = *(const float4*)(lnqg+d0);
      #pragma unroll
      for(int jj=0;jj<4;jj++){
        float w4[4];
        #pragma unroll
        for(int ii=0;ii<4;ii++) w4[ii]=0.125f*lq4[ii]*acc[ii][jj];
        *(float4*)&M2T[e0+jj][d0] = *(float4*)w4;
      }
    }
    __syncthreads();
    if(tid<64){ // vtmp3[e] = sum_c qb[c]*wm[c,e]
      int e=tid; float s=0.f; for(int c2=0;c2<64;c2++) s=fmaf(vtmp[0][c2], M1[c2][e], s); vtmp[3][e]=s;
    } else if(tid<128){ // v4[d] = 0.125*lnqg[d]*sum_c wq[c,d]*bm2[c]
      int d=tid-64; float s=0.f; for(int c2=0;c2<64;c2++) s=fmaf(M0[c2][d], vtmp[1][c2], s);
      vqp[4*64+d]=0.125f*lnqg[d]*s;
    }
    __syncthreads();
    // overwrite M0 with wkL[e][o] = lnkg[e]*wk[e,o]
    for(int i=tid;i<4096;i+=256){ int e=i>>6,o=i&63; M0[e][o]=aux[3][e]*wk[i]; }
    __syncthreads();
    // WQ[d][o] = lnfg[o]*sum_e M2T[e][d]*wkL[e][o]
    {
      int d0=(tid>>4)*4, o0=(tid&15)*4;
      float acc[4][4]={};
      for(int e=0;e<64;e++) MM44(&M2T[e][d0], &M0[e][o0]);
      float lf4[4]; *(float4*)lf4 = *(const float4*)(lnfg+o0);
      #pragma unroll
      for(int ii=0;ii<4;ii++){
        float w4[4];
        #pragma unroll
        for(int jj=0;jj<4;jj++) w4[jj]=lf4[jj]*acc[ii][jj];
        *(float4*)(WQp + (d0+ii)*64 + o0) = *(float4*)w4;
      }
    }
    // finishers: all LDS-resident
    if(tid<64){ int o=tid; float s=0.f;
      for(int e=0;e<64;e++) s=fmaf(vtmp[3][e], M0[e][o], s);
      bq2p[o]=lnfg[o]*s; }
    else if(tid<128){ int d=tid-64; float s1=0.f,sx=0.f,sy=0.f,s3=0.f;
      for(int e=0;e<64;e++){ float pe=M2T[e][d]*aux[3][e];
        s1+=pe; sx+=pe*aux[0][e]; sy+=pe*aux[1][e]; s3+=pe*(aux[2][e]+vtmp[2][e]); }
      vqp[0*64+d]=s1; vqp[1*64+d]=sx; vqp[2*64+d]=sy; vqp[3*64+d]=s3; }
    else if(tid<192){ // wave-parallel csc (wave 2, lane e)
      int e=tid-128;
      float qe=vtmp[3][e]*aux[3][e];
      float c0=wsum64(qe);
      float c1=wsum64(qe*aux[0][e]);
      float c2=wsum64(qe*aux[1][e]);
      float c3=wsum64(qe*(aux[2][e]+vtmp[2][e]));
      float c4=wsum64(vtmp[0][e]*vtmp[1][e]);
      if(e==0){ cscp[0]=c0; cscp[1]=c1; cscp[2]=c2; cscp[3]=c3; cscp[4]=c4; }
    }
  } else {
    // gru-side collapse: WC[d][o] = lnfg[d]*sum_e wv[e,d]*lnkg[e]*wm[o,e]
    for(int i=tid;i<4096;i+=256){ int r=i>>6,c2=i&63; M0[r][c2]=wv[i]*lnkg[r]; M1[c2][r]=wm[i]; }
    if(tid>=192){ int l=tid-192;
      float4 w4 = *(const float4*)(wg + l*4);
      aux[0][l]=w4.x-w4.z; aux[1][l]=w4.y-w4.w; aux[2][l]=bg[l]; aux[3][l]=lnkg[l];
    }
    __syncthreads();
    if(tid<64){ float s=0.f; const float* wr=wv+tid*64;
      for(int d=0;d<64;d++) s+=lnfb[d]*wr[d]; vtmp[0][tid]=s; } // fvb
    __syncthreads();
    {
      int d0=(tid>>4)*4, o0=(tid&15)*4;
      float acc[4][4]={};
      for(int e=0;e<64;e++) MM44(&M0[e][d0], &M1[e][o0]);
      float lf4[4]; *(float4*)lf4 = *(const float4*)(lnfg+d0);
      #pragma unroll
      for(int ii=0;ii<4;ii++){
        float w4[4];
        #pragma unroll
        for(int jj=0;jj<4;jj++) w4[jj]=lf4[ii]*acc[ii][jj];
        *(float4*)(WCp + (d0+ii)*64 + o0) = *(float4*)w4;
      }
    }
    if(tid<64){ int o=tid; float s1=0.f,s2=0.f,s3=0.f,s4=0.f;
      for(int e=0;e<64;e++){ float we=aux[3][e]*M1[e][o];
        s1+=we*(vtmp[0][e]+aux[2][e]); s2+=we*aux[0][e]; s3+=we*aux[1][e]; s4+=we; }
      uvp[0*64+o]=s1; uvp[1*64+o]=s2; uvp[2*64+o]=s3; uvp[3*64+o]=s4; }
  }
  #undef MM44
}

// feat LN -> A (bf16); transient MFMA fk/fv rows -> per-row stat float4s; color LN.
// Tail blocks (bid >= 1024): first-iteration slot preamble (slotq0) per bk,
// reading only k_pre outputs (sl0, WQ, bq2, vq, csc) -> qsb (bf16), cst.
__global__ __launch_bounds__(256) void k_featln(const float* __restrict__ feat,
    const float* __restrict__ wk, const float* __restrict__ wv, const float* __restrict__ gf,
    const float* __restrict__ fkb, const float* __restrict__ fvb,
    const float* __restrict__ wgx, const float* __restrict__ wgy, const float* __restrict__ bg,
    const float* __restrict__ fc, const float* __restrict__ gc, const float* __restrict__ bc,
    uint16_t* __restrict__ Aout, float4* __restrict__ kstat, float4* __restrict__ vstat,
    float* __restrict__ fcn,
    const float* __restrict__ sl0, const float* __restrict__ WQc,
    const float* __restrict__ bq2c, const float* __restrict__ vqc,
    const float* __restrict__ cscc, const float* __restrict__ gsc,
    uint16_t* __restrict__ qsb, float* __restrict__ cstq){
  int tid=threadIdx.x, wid=tid>>6, lane=tid&63;
  if(blockIdx.x >= (B_*N_)/64){
    // ---- slotq0 tail ----
    __shared__ float vv[64];
    __shared__ float red4[4][64];
    int bk = blockIdx.x - (B_*N_)/64;
    float mwgx=gsc[0], mwgy=gsc[1], mbg=gsc[2];
    if(wid==0){
      float cur = sl0[bk*64+lane];
      float m=wsum64(cur)*(1.f/64.f); float df=cur-m;
      float var=wsum64(df*df)*(1.f/64.f);
      float LNc=df*rsqrtf(var+EPS);
      vv[lane]=LNc;
      float s1=wsum64(LNc*vqc[lane])     + cscc[0];
      float c1=wsum64(LNc*vqc[64+lane])  + cscc[1];
      float c2=wsum64(LNc*vqc[128+lane]) + cscc[2];
      float c3=wsum64(LNc*vqc[192+lane]) + cscc[3];
      float c4=wsum64(LNc*vqc[256+lane]) + cscc[4];
      if(lane==0){
        float* cp = cstq + bk*8;
        cp[0]=c1-s1*mwgx; cp[1]=c2-s1*mwgy; cp[2]=c3-s1*mbg; cp[3]=s1; cp[4]=c4;
      }
    }
    __syncthreads();
    { float p_=0.f;
      #pragma unroll
      for(int dd=0;dd<16;dd++) p_ = fmaf(vv[wid*16+dd], WQc[(wid*16+dd)*64+lane], p_);
      red4[wid][lane]=p_; }
    __syncthreads();
    if(wid==0)
      qsb[bk*64+lane] = f2bf(red4[0][lane]+red4[1][lane]+red4[2][lane]+red4[3][lane] + bq2c[lane]);
    return;
  }
  int q=lane>>4, c=lane&15;
  size_t row = (size_t)blockIdx.x*64 + wid*16 + c;
  const float* xp = feat + row*64;
  float x[16];
  *(float4*)&x[0]  = *(const float4*)(xp + q*8);
  *(float4*)&x[4]  = *(const float4*)(xp + q*8 + 4);
  *(float4*)&x[8]  = *(const float4*)(xp + 32 + q*8);
  *(float4*)&x[12] = *(const float4*)(xp + 36 + q*8);
  float s=0.f;
  #pragma unroll
  for(int i=0;i<16;i++) s+=x[i];
  s += __shfl_xor(s,16,64); s += __shfl_xor(s,32,64);
  float mean = s*(1.f/64.f);
  float v=0.f;
  #pragma unroll
  for(int i=0;i<16;i++){ float d=x[i]-mean; v+=d*d; }
  v += __shfl_xor(v,16,64); v += __shfl_xor(v,32,64);
  float rs = rsqrtf(v*(1.f/64.f)+EPS);
  float gl[16];
  *(float4*)&gl[0]  = *(const float4*)(gf + q*8);
  *(float4*)&gl[4]  = *(const float4*)(gf + q*8 + 4);
  *(float4*)&gl[8]  = *(const float4*)(gf + 32 + q*8);
  *(float4*)&gl[12] = *(const float4*)(gf + 36 + q*8);
  bf16x8 A0, A1;
  #pragma unroll
  for(int j=0;j<8;j++){
    A0[j] = (short)f2bf((x[j]  -mean)*rs);
    A1[j] = (short)f2bf((x[8+j]-mean)*rs);
  }
  *(bf16x8*)(Aout + row*64 + q*8) = A0;
  *(bf16x8*)(Aout + row*64 + 32 + q*8) = A1;
  float wgxl[4][4], wgyl[4][4], bgl[4][4];
  #pragma unroll
  for(int ot=0;ot<4;ot++){
    *(float4*)&wgxl[ot][0] = *(const float4*)(wgx + ot*16 + q*4);
    *(float4*)&wgyl[ot][0] = *(const float4*)(wgy + ot*16 + q*4);
    *(float4*)&bgl[ot][0]  = *(const float4*)(bg + ot*16 + q*4);
  }
  #pragma unroll
  for(int mat=0;mat<2;mat++){
    const float* w = mat? wv : wk;
    const float* fb = mat? fvb : fkb;
    float ss=0.f, s2=0.f, dx=0.f, dy=0.f, db=0.f;
    #pragma unroll
    for(int ot=0; ot<4; ot++){
      const float* wp = w + (size_t)(ot*16+c)*64 + q*8;
      bf16x8 W0, W1;
      #pragma unroll
      for(int j=0;j<8;j++){ W0[j]=(short)f2bf(wp[j]*gl[j]); W1[j]=(short)f2bf(wp[32+j]*gl[8+j]); }
      float4 bq = *(const float4*)(fb + ot*16 + q*4);
      f32x4 acc = {bq.x,bq.y,bq.z,bq.w};
      acc = __builtin_amdgcn_mfma_f32_16x16x32_bf16(W0, A0, acc, 0,0,0);
      acc = __builtin_amdgcn_mfma_f32_16x16x32_bf16(W1, A1, acc, 0,0,0);
      #pragma unroll
      for(int r=0;r<4;r++){
        float a=acc[r];
        ss+=a; s2+=a*a;
        dx = fmaf(a, wgxl[ot][r], dx);
        dy = fmaf(a, wgyl[ot][r], dy);
        db = fmaf(a, bgl[ot][r], db);
      }
    }
    ss += __shfl_xor(ss,16,64); ss += __shfl_xor(ss,32,64);
    s2 += __shfl_xor(s2,16,64); s2 += __shfl_xor(s2,32,64);
    dx += __shfl_xor(dx,16,64); dx += __shfl_xor(dx,32,64);
    dy += __shfl_xor(dy,16,64); dy += __shfl_xor(dy,32,64);
    db += __shfl_xor(db,16,64); db += __shfl_xor(db,32,64);
    if(lane<16){
      size_t row2 = (size_t)blockIdx.x*64 + wid*16 + lane;
      float4 st = { ss*(1.f/64.f), s2*(1.f/64.f)+db*(1.f/32.f), dx*(1.f/32.f), dy*(1.f/32.f) };
      (mat? vstat : kstat)[row2] = st;
    }
  }
  int r16=tid>>4, cc=tid&15;
  #pragma unroll
  for(int i=0;i<4;i++){
    size_t row2 = (size_t)blockIdx.x*64 + i*16 + r16;
    float xv = fc[row2*16+cc];
    float sc=xv;
    #pragma unroll
    for(int o=1;o<16;o<<=1) sc += __shfl_xor(sc,o,16);
    float m2 = sc*(1.f/16.f);
    float df = xv-m2;
    float v2 = df*df;
    #pragma unroll
    for(int o=1;o<16;o<<=1) v2 += __shfl_xor(v2,o,16);
    fcn[row2*16+cc] = df*rsqrtf(v2*(1.f/16.f)+EPS)*gc[cc] + bc[cc];
  }
}

// Block-parallel per-bk GRU preamble: collapsed merge + single-matvec q chain.
// 80 blocks x 256 threads. qs written as bf16.
__global__ __launch_bounds__(256) void k_slotq(
    const float* __restrict__ slot_prev, float* __restrict__ slot_cur,
    const float* __restrict__ part, const float* __restrict__ pscal,
    const float* __restrict__ red_in,
    const float* __restrict__ gw,
    const float* __restrict__ bih, const float* __restrict__ bhh,
    const float* __restrict__ wrpT, const float* __restrict__ br2,
    const float* __restrict__ bm2,
    const float* __restrict__ WQ, const float* __restrict__ bq2,
    const float* __restrict__ WC, const float* __restrict__ uvec,
    const float* __restrict__ vq, const float* __restrict__ csc,
    const float* __restrict__ gscal,
    uint16_t* __restrict__ qs_out, float* __restrict__ cst_out){
  __shared__ float vv[64], vh[64];
  __shared__ float red6[4][64][6];
  __shared__ float lamb[NC_];
  __shared__ float sc4[4];
  int bk=blockIdx.x;
  int tid=threadIdx.x, wid=tid>>6, lane=tid&63;
  int o=lane, qq=wid;
  float mwgx=gscal[0], mwgy=gscal[1], mbg=gscal[2];

  #define MV(Wptr) { float p_=0.f; \
      _Pragma("unroll") \
      for(int dd=0;dd<16;dd++) p_ = fmaf(vv[qq*16+dd], (Wptr)[(qq*16+dd)*64+o], p_); \
      red6[qq][o][0]=p_; } __syncthreads();
  #define SUM0 (red6[0][lane][0]+red6[1][lane][0]+red6[2][lane][0]+red6[3][lane][0])

  float cur=0.f, hp=0.f;
  {
    if(wid==0){
      // lane-parallel chunk merge (lane<NC_)
      float m_l = (lane<NC_)? red_in[((size_t)bk*NC_+lane)*4]   : -1e30f;
      float s_l = (lane<NC_)? red_in[((size_t)bk*NC_+lane)*4+1] : 0.f;
      float M = wmax64(m_l);
      float eu = (lane<NC_)? __expf(m_l-M) : 0.f;
      float S = wsum64(s_l*eu);
      float lam = eu/S;
      if(lane<NC_) lamb[lane]=lam;
      float p0 = (lane<NC_)? pscal[((size_t)bk*NC_+lane)*4+0] : 0.f;
      float p1 = (lane<NC_)? pscal[((size_t)bk*NC_+lane)*4+1] : 0.f;
      float p2 = (lane<NC_)? pscal[((size_t)bk*NC_+lane)*4+2] : 0.f;
      float p3 = (lane<NC_)? pscal[((size_t)bk*NC_+lane)*4+3] : 0.f;
      float As = wsum64(lam*p0), Ax = wsum64(lam*p1);
      float Ay = wsum64(lam*p2), Am = wsum64(lam*p3);
      if(lane==0){ sc4[0]=As; sc4[1]=Ax; sc4[2]=Ay; sc4[3]=Am; }
    }
    __syncthreads();
    { // sA partials: wave qq handles chunks qq*8..qq*8+7
      float p_=0.f;
      #pragma unroll
      for(int j=0;j<8;j++){
        int cc = qq*8+j;
        p_ = fmaf(lamb[cc], part[((size_t)bk*NC_+cc)*64+o], p_);
      }
      red6[qq][o][0]=p_;
    }
    __syncthreads();
    if(wid==0) vv[lane] = SUM0;        // sA (WC absorbs lnfg)
    __syncthreads();
    MV(WC);
    if(wid==0){
      float As=sc4[0],Ax=sc4[1],Ay=sc4[2],Am=sc4[3];
      float x_ = SUM0 + As*uvec[lane] + Ax*uvec[64+lane] + Ay*uvec[128+lane]
               - Am*uvec[192+lane] + bm2[lane];
      hp = slot_prev[bk*64+lane];
      vv[lane]=x_; vh[lane]=hp;
    }
    __syncthreads();
    {
      float p0=0.f,p1=0.f,p2=0.f,p3=0.f,p4=0.f,p5=0.f;
      #pragma unroll
      for(int dd=0;dd<16;dd++){
        int d = qq*16+dd;
        float xd=vv[d], hd=vh[d];
        p0 = fmaf(xd, gw[d*64+o], p0);
        p1 = fmaf(xd, gw[4096+d*64+o], p1);
        p2 = fmaf(xd, gw[8192+d*64+o], p2);
        p3 = fmaf(hd, gw[12288+d*64+o], p3);
        p4 = fmaf(hd, gw[16384+d*64+o], p4);
        p5 = fmaf(hd, gw[20480+d*64+o], p5);
      }
      red6[qq][o][0]=p0; red6[qq][o][1]=p1; red6[qq][o][2]=p2;
      red6[qq][o][3]=p3; red6[qq][o][4]=p4; red6[qq][o][5]=p5;
    }
    __syncthreads();
    if(wid==0){
      float gir=bih[lane], giz=bih[64+lane], gin=bih[128+lane];
      float ghr=bhh[lane], ghz=bhh[64+lane], ghn=bhh[128+lane];
      #pragma unroll
      for(int w=0;w<4;w++){
        gir+=red6[w][lane][0]; giz+=red6[w][lane][1]; gin+=red6[w][lane][2];
        ghr+=red6[w][lane][3]; ghz+=red6[w][lane][4]; ghn+=red6[w][lane][5];
      }
      float r=1.f/(1.f+__expf(-(gir+ghr)));
      float z=1.f/(1.f+__expf(-(giz+ghz)));
      float nn=tanhf(gin+r*ghn);
      float sp=(1.f-z)*nn+z*hp;
      float m=wsum64(sp)*(1.f/64.f); float df=sp-m;
      float var=wsum64(df*df)*(1.f/64.f);
      vv[lane]=df*rsqrtf(var+EPS);
    }
    __syncthreads();
    MV(wrpT);
    if(wid==0){
      cur = SUM0 + br2[lane] + hp;
      slot_cur[bk*64+lane]=cur;
    }
  }
  __syncthreads();
  if(wid==0){
    float m=wsum64(cur)*(1.f/64.f); float df=cur-m;
    float var=wsum64(df*df)*(1.f/64.f);
    float LNc=df*rsqrtf(var+EPS);
    vv[lane]=LNc;
    float s1=wsum64(LNc*vq[lane])     + csc[0];
    float c1=wsum64(LNc*vq[64+lane])  + csc[1];
    float c2=wsum64(LNc*vq[128+lane]) + csc[2];
    float c3=wsum64(LNc*vq[192+lane]) + csc[3];
    float c4=wsum64(LNc*vq[256+lane]) + csc[4];
    if(lane==0){
      float* cp = cst_out + bk*8;
      cp[0]=c1-s1*mwgx; cp[1]=c2-s1*mwgy; cp[2]=c3-s1*mbg; cp[3]=s1; cp[4]=c4;
    }
  }
  __syncthreads();
  MV(WQ);
  if(wid==0) qs_out[bk*64+lane] = f2bf(SUM0 + bq2[lane]);
  #undef MV
  #undef SUM0
}

// Slot-amortized attention: block = (chunk CS_=128, b), all K=5 slots.
// Phase 2 split across all 4 waves: waves 0-1 -> slots 0-2, waves 2-3 -> slots 3-4.
// Grid (NC_=32, B_) = 512 blocks.
template<bool FINAL>
__global__ __launch_bounds__(256) void k_attn(const uint16_t* __restrict__ Aw,
    const float4* __restrict__ kstat, const float4* __restrict__ vstat,
    const uint16_t* __restrict__ qsg, const float* __restrict__ cstg,
    const float* __restrict__ gscal, const float* __restrict__ ws_fg,
    float* __restrict__ lgt, float* __restrict__ red_out,
    float* __restrict__ part_o, float* __restrict__ pscal_o){
  __shared__ uint32_t As_[CS_*32];      // 16KB: 128 rows x 64 bf16
  __shared__ __align__(16) float dps[5][CS_+4];  // dots -> weights
  __shared__ float pw[4][5][64];
  __shared__ float rm[2][5], rn[2][5];
  __shared__ float rsc[2][5][5];
  __shared__ float cstl[5][5];
  __shared__ float fgl[5][2];
  int chunk=blockIdx.x, b=blockIdx.y;
  int tid=threadIdx.x, wid=tid>>6, lane=tid&63;
  int c=lane&15, q=lane>>4;
  float mwgx=gscal[0], mwgy=gscal[1], mbg=gscal[2];
  float g1=gscal[3], g2=gscal[4], g3=gscal[5], g4=gscal[6], g5=gscal[7], g6=gscal[8];

  // stage A chunk -> LDS (only needed for accumulation; dead in FINAL)
  if(!FINAL){
    const uint4* Ag = (const uint4*)(Aw + ((size_t)b*N_ + chunk*CS_)*64);
    #pragma unroll
    for(int jj=0;jj<4;jj++){
      int f = jj*256 + tid;
      *(uint4*)(As_ + f*4) = Ag[f];
    }
  }
  if(tid<25) cstl[tid/5][tid%5] = cstg[(b*K_ + tid/5)*8 + (tid%5)];
  if(tid>=32 && tid<42){ int i2=tid-32; fgl[i2>>1][i2&1] = ws_fg[i2]; }
  // phase-2 mapping: all threads active. half=row-half, slots by wave pair.
  int half = wid & 1;
  int r128 = half*64 + lane;            // row within chunk
  int nrow = chunk*CS_ + r128;
  int k0 = (wid < 2) ? 0 : 3;
  int nk = (wid < 2) ? 3 : 2;
  float4 st = kstat[(size_t)b*N_ + nrow];
  float4 sv;
  if(!FINAL) sv = vstat[(size_t)b*N_ + nrow];
  float gx = -1.f + (2.f/63.f)*(nrow&63);
  float gy = -1.f + (2.f/63.f)*(nrow>>6);
  __syncthreads();

  // phase 1: MFMA dots; B-frags from GLOBAL (aligned); 2 tiles per wave
  {
    bf16x8 QF0={0,0,0,0,0,0,0,0}, QF1={0,0,0,0,0,0,0,0};
    if(c<5){
      const uint16_t* qpp = qsg + (b*K_+c)*64;
      QF0 = *(const bf16x8*)(qpp + q*8);
      QF1 = *(const bf16x8*)(qpp + 32 + q*8);
    }
    const uint16_t* Abase = Aw + ((size_t)b*N_ + chunk*CS_)*64;
    #pragma unroll
    for(int it=0;it<2;it++){
      int tile = wid*32 + it*16;
      const uint16_t* rp = Abase + (size_t)(tile+c)*64;
      bf16x8 BF0 = *(const bf16x8*)(rp + q*8);
      bf16x8 BF1 = *(const bf16x8*)(rp + 32 + q*8);
      f32x4 acc = {0.f,0.f,0.f,0.f};
      acc = __builtin_amdgcn_mfma_f32_16x16x32_bf16(QF0, BF0, acc, 0,0,0);
      acc = __builtin_amdgcn_mfma_f32_16x16x32_bf16(QF1, BF1, acc, 0,0,0);
      #pragma unroll
      for(int r=0;r<4;r++){
        int s = q*4+r;
        if(s<5) dps[s][tile+c]=acc[r];
      }
    }
  }
  __syncthreads();

  // phase 2a: logits + per-half max (per-thread serial chain: <=3 slots)
  float l3[3], w3[3];
  #pragma unroll
  for(int j=0;j<3;j++){
    if(j<nk){
      int k=k0+j;
      float rx = gx - fgl[k][0], ry = gy - fgl[k][1];
      float CX=cstl[k][0], CY=cstl[k][1], C0=cstl[k][2], S1=cstl[k][3], C4=cstl[k][4];
      float quad = g1*rx*rx + g2*ry*ry + g3*rx*ry + g4*rx + g5*ry + g6;
      float mu = st.x + rx*mwgx + ry*mwgy + mbg;
      float var = st.y + rx*st.z + ry*st.w + quad - mu*mu;
      float rsn = rsqrtf(var+EPS);
      float l = rsn*(dps[k][r128] + rx*CX + ry*CY + C0 - S1*st.x) + C4;
      l3[j]=l;
      float wmx = wmax64(l);
      if(lane==0) rm[half][k]=wmx;
      if(FINAL){ float mn=wmin64(l); if(lane==0) rn[half][k]=mn; }
    }
  }
  __syncthreads();
  // phase 2b: exp + weighted sums
  #pragma unroll
  for(int j=0;j<3;j++){
    if(j<nk){
      int k=k0+j;
      float m_c = fmaxf(rm[0][k], rm[1][k]);
      float e = __expf(l3[j]-m_c);
      float scq = wsum64(e);
      if(!FINAL){
        float rx = gx - fgl[k][0], ry = gy - fgl[k][1];
        float quad = g1*rx*rx + g2*ry*ry + g3*rx*ry + g4*rx + g5*ry + g6;
        float muV = sv.x + rx*mwgx + ry*mwgy + mbg;
        float varV = sv.y + rx*sv.z + ry*sv.w + quad - muV*muV;
        float rsv_ = rsqrtf(varV+EPS);
        float w_ = e*rsv_;
        w3[j]=w_;
        float As2=wsum64(w_), Ax2=wsum64(w_*rx), Ay2=wsum64(w_*ry), Am2=wsum64(w_*muV);
        if(lane==0){ rsc[half][k][0]=scq; rsc[half][k][1]=As2; rsc[half][k][2]=Ax2;
                     rsc[half][k][3]=Ay2; rsc[half][k][4]=Am2; }
      } else {
        lgt[(size_t)(b*K_+k)*N_ + nrow] = l3[j];
        if(lane==0) rsc[half][k][0]=scq;
      }
    }
  }
  __syncthreads();
  if(tid<5){
    int k=tid;
    size_t idx = ((size_t)(b*K_+k)*NC_+chunk)*4;
    red_out[idx+0]=fmaxf(rm[0][k],rm[1][k]);
    red_out[idx+1]=rsc[0][k][0]+rsc[1][k][0];
    if(FINAL) red_out[idx+2]=fminf(rn[0][k],rn[1][k]);
    if(!FINAL){
      pscal_o[idx+0]=rsc[0][k][1]+rsc[1][k][1];
      pscal_o[idx+1]=rsc[0][k][2]+rsc[1][k][2];
      pscal_o[idx+2]=rsc[0][k][3]+rsc[1][k][3];
      pscal_o[idx+3]=rsc[0][k][4]+rsc[1][k][4];
    }
  }
  if(!FINAL){
    #pragma unroll
    for(int j=0;j<3;j++)
      if(j<nk) dps[k0+j][r128]=w3[j];
  }

  // accumulation: part[k][ch] = sum_row w_k[row]*A[row][ch]  (4-row batched dps reads)
  if(!FINAL){
    __syncthreads();
    const uint16_t* Au = (const uint16_t*)As_;
    float a0=0.f,a1=0.f,a2=0.f,a3=0.f,a4=0.f;
    #pragma unroll
    for(int rb=0;rb<8;rb++){
      int row0 = wid*32 + rb*4;
      float4 d0 = *(const float4*)&dps[0][row0];
      float4 d1 = *(const float4*)&dps[1][row0];
      float4 d2 = *(const float4*)&dps[2][row0];
      float4 d3 = *(const float4*)&dps[3][row0];
      float4 d4 = *(const float4*)&dps[4][row0];
      float av0 = __uint_as_float(((uint32_t)Au[(row0+0)*64+lane])<<16);
      float av1 = __uint_as_float(((uint32_t)Au[(row0+1)*64+lane])<<16);
      float av2 = __uint_as_float(((uint32_t)Au[(row0+2)*64+lane])<<16);
      float av3 = __uint_as_float(((uint32_t)Au[(row0+3)*64+lane])<<16);
      a0=fmaf(d0.x,av0,a0); a0=fmaf(d0.y,av1,a0); a0=fmaf(d0.z,av2,a0); a0=fmaf(d0.w,av3,a0);
      a1=fmaf(d1.x,av0,a1); a1=fmaf(d1.y,av1,a1); a1=fmaf(d1.z,av2,a1); a1=fmaf(d1.w,av3,a1);
      a2=fmaf(d2.x,av0,a2); a2=fmaf(d2.y,av1,a2); a2=fmaf(d2.z,av2,a2); a2=fmaf(d2.w,av3,a2);
      a3=fmaf(d3.x,av0,a3); a3=fmaf(d3.y,av1,a3); a3=fmaf(d3.z,av2,a3); a3=fmaf(d3.w,av3,a3);
      a4=fmaf(d4.x,av0,a4); a4=fmaf(d4.y,av1,a4); a4=fmaf(d4.z,av2,a4); a4=fmaf(d4.w,av3,a4);
    }
    pw[wid][0][lane]=a0; pw[wid][1][lane]=a1; pw[wid][2][lane]=a2;
    pw[wid][3][lane]=a3; pw[wid][4][lane]=a4;
    __syncthreads();
    if(tid<64){
      #pragma unroll
      for(int k=0;k<5;k++){
        float s2 = pw[0][k][tid]+pw[1][k][tid]+pw[2][k][tid]+pw[3][k][tid];
        part_o[((size_t)(b*K_+k)*NC_+chunk)*64 + tid] = s2;
      }
    }
  }
}

// fin: p from global stats; out_attn; color partial atomicAdd; slot write (chunk 0)
__global__ __launch_bounds__(256) void k_fin(const float* __restrict__ lgt,
    const float* __restrict__ red, const float* __restrict__ featc,
    const float* __restrict__ sl1, float* __restrict__ out_slot,
    float* __restrict__ out_attn){
  __shared__ float psp[CS_];
  __shared__ float pcz[4][16];
  int chunk=blockIdx.x, bk=blockIdx.y, b=bk/K_;
  int tid=threadIdx.x, wid=tid>>6, lane=tid&63, sub=lane>>4, c4=lane&15;
  const float* rp = red + (size_t)bk*NC_*4;
  float M=-1e30f;
  #pragma unroll
  for(int i=0;i<NC_;i++) M = fmaxf(M, rp[i*4]);
  float S=0.f;
  #pragma unroll
  for(int i=0;i<NC_;i++) S += rp[i*4+1]*__expf(rp[i*4]-M);
  float invS = 1.f/S;
  float LMIN=1e30f;
  #pragma unroll
  for(int i=0;i<NC_;i++) LMIN=fminf(LMIN, rp[i*4+2]);
  float amin = __expf(LMIN-M)*invS;
  float dinv = 1.f/(invS - amin + 1e-5f);
  const float* lp = lgt + (size_t)bk*N_ + chunk*CS_;
  if(tid<CS_){
    float p = __expf(lp[tid]-M)*invS;
    psp[tid]=p;
    out_attn[(size_t)bk*N_ + chunk*CS_ + tid] = (p - amin)*dinv;
  }
  __syncthreads();
  const float* Fb = featc + ((size_t)b*N_ + chunk*CS_)*16;
  float ac=0.f;
  for(int t=0;t<8;t++){
    int n = wid*32 + t*4 + sub;
    ac += psp[n]*Fb[(size_t)n*16 + c4];
  }
  ac+=__shfl_xor(ac,16,64); ac+=__shfl_xor(ac,32,64);
  if(lane<16) pcz[wid][lane]=ac;
  __syncthreads();
  if(tid<16){
    float s2 = pcz[0][tid]+pcz[1][tid]+pcz[2][tid]+pcz[3][tid];
    atomicAdd(&out_slot[bk*80+64+tid], s2);
  }
  if(chunk==0 && tid<64) out_slot[bk*80+tid]=sl1[bk*64+tid];
}

extern "C" void kernel_launch(void* const* d_in, const int* in_sizes, int n_in,
                              void* d_out, int out_size, void* d_ws, size_t ws_size,
                              hipStream_t stream){
  (void)in_sizes; (void)n_in; (void)out_size; (void)ws_size;
  const float* feat = (const float*)d_in[0];
  const float* featc= (const float*)d_in[1];
  const float* mask = (const float*)d_in[2];
  const float* noise= (const float*)d_in[3];
  const float* mu   = (const float*)d_in[4];
  const float* lsg  = (const float*)d_in[5];
  const float* wg   = (const float*)d_in[6];
  const float* bg   = (const float*)d_in[7];
  const float* wk   = (const float*)d_in[8];
  const float* wv   = (const float*)d_in[9];
  const float* lnkg = (const float*)d_in[10];
  const float* lnkb = (const float*)d_in[11];
  const float* wm   = (const float*)d_in[12];
  const float* bm   = (const float*)d_in[13];
  const float* lnqg = (const float*)d_in[14];
  const float* lnqb = (const float*)d_in[15];
  const float* wq   = (const float*)d_in[16];
  const float* wih  = (const float*)d_in[17];
  const float* whh  = (const float*)d_in[18];
  const float* bih  = (const float*)d_in[19];
  const float* bhh  = (const float*)d_in[20];
  const float* lnfg = (const float*)d_in[21];
  const float* lnfb = (const float*)d_in[22];
  const float* lncg = (const float*)d_in[23];
  const float* lncb = (const float*)d_in[24];
  const float* lnrg = (const float*)d_in[25];
  const float* lnrb = (const float*)d_in[26];
  const float* wres = (const float*)d_in[27];
  const float* bres = (const float*)d_in[28];

  float* out = (float*)d_out;
  float* out_slot = out;          // (B,K,80)
  float* out_fg   = out + 6400;   // (B,K,2)
  float* out_attn = out + 6560;   // (B,K,N)

  float* wsf     = (float*)d_ws;
  float* ws_fg   = wsf;                                // 16
  float* ws_bm2  = wsf + 16;                           // 64
  float* ws_fkb  = ws_bm2 + 64;                        // 64
  float* ws_fvb  = ws_fkb + 64;                        // 64
  float* ws_qb   = ws_fvb + 64;                        // 64
  float* ws_br2  = ws_qb + 64;                         // 64
  float* ws_wgx  = ws_br2 + 64;                        // 64
  float* ws_wgy  = ws_wgx + 64;                        // 64
  float* ws_gs   = ws_wgy + 64;                        // 16
  float* ws_wrpT = ws_gs + 16;                         // 4096
  float* ws_gw   = ws_wrpT + 4096;                     // 24576
  float* ws_WQ   = ws_gw + 24576;                      // 4096
  float* ws_WC   = ws_WQ + 4096;                       // 4096
  float* ws_bq2  = ws_WC + 4096;                       // 64
  float* ws_u    = ws_bq2 + 64;                        // 256
  float* ws_vq   = ws_u + 256;                         // 320
  float* ws_csc  = ws_vq + 320;                        // 16
  uint16_t* ws_qsb = (uint16_t*)(ws_csc + 16);         // 5120 bf16 (in 5120-float slot)
  float* ws_cst  = ws_csc + 16 + 5120;                 // 640
  float* ws_fc   = ws_cst + 640;                       // B*N*C
  float* ws_sl0  = ws_fc + (size_t)B_*N_*C_;           // 5120
  float* ws_sl1  = ws_sl0 + B_*K_*D_;                  // 5120
  float* ws_lgt  = ws_sl1 + B_*K_*D_;                  // B*K*N
  float* ws_red0 = ws_lgt + (size_t)B_*K_*N_;          // 80*NC*4
  float* ws_red1 = ws_red0 + B_*K_*NC_*4;              // 80*NC*4
  float* ws_prt0 = ws_red1 + B_*K_*NC_*4;              // 80*NC*64
  float* ws_prt1 = ws_prt0 + (size_t)B_*K_*NC_*64;     // 80*NC*64
  float* ws_psc0 = ws_prt1 + (size_t)B_*K_*NC_*64;     // 80*NC*4
  float* ws_psc1 = ws_psc0 + B_*K_*NC_*4;              // 80*NC*4
  float4* ws_kst = (float4*)(ws_psc1 + B_*K_*NC_*4);   // B*N float4
  float4* ws_vst = ws_kst + (size_t)B_*N_;             // B*N float4
  uint16_t* ws_A = (uint16_t*)(ws_vst + (size_t)B_*N_);// B*N*64 bf16

  k_pre<<<141,256,0,stream>>>(mask,noise,mu,lsg, wm,bm,lnkb, wk,wv,lnfb,
                              wq,lnqg,lnqb, wres,bres,lnrg,lnrb, wih,whh, wg,bg,
                              lnfg,lnkg,
                              ws_fg,out_fg, ws_bm2,ws_fkb,ws_fvb,ws_qb,ws_br2,
                              ws_wgx,ws_wgy,ws_gs,
                              ws_wrpT, ws_gw, ws_sl0, out_slot,
                              ws_WQ, ws_WC, ws_bq2, ws_u, ws_vq, ws_csc);
  // featln + slotq0 tail (80 extra blocks)
  k_featln<<<(B_*N_)/64 + B_*K_,256,0,stream>>>(feat,wk,wv,lnfg,ws_fkb,ws_fvb,
                                        ws_wgx,ws_wgy,bg,
                                        featc,lncg,lncb,
                                        ws_A,ws_kst,ws_vst,ws_fc,
                                        ws_sl0, ws_WQ, ws_bq2, ws_vq, ws_csc, ws_gs,
                                        ws_qsb, ws_cst);

  dim3 agrid(NC_,B_);
  #define SQ_ARGS(SPREV,SCUR,PIN,SCIN,RIN) SPREV,SCUR,PIN,SCIN,RIN,ws_gw, \
      bih,bhh,ws_wrpT,ws_br2,ws_bm2, ws_WQ,ws_bq2, ws_WC,ws_u, ws_vq,ws_csc, \
      ws_gs, ws_qsb,ws_cst
  #define AT_ARGS(ROUT,POUT,SCOUT) ws_A,ws_kst,ws_vst,ws_qsb,ws_cst,ws_gs,ws_fg, \
      ws_lgt,ROUT,POUT,SCOUT

  k_attn<false><<<agrid,256,0,stream>>>(AT_ARGS(ws_red0,ws_prt0,ws_psc0));
  k_slotq<<<B_*K_,256,0,stream>>>(SQ_ARGS(ws_sl0,ws_sl1,ws_prt0,ws_psc0,ws_red0));
  k_attn<false><<<agrid,256,0,stream>>>(AT_ARGS(ws_red1,ws_prt1,ws_psc1));
  k_slotq<<<B_*K_,256,0,stream>>>(SQ_ARGS(ws_sl1,ws_sl0,ws_prt1,ws_psc1,ws_red1));
  k_attn<false><<<agrid,256,0,stream>>>(AT_ARGS(ws_red0,ws_prt0,ws_psc0));
  k_slotq<<<B_*K_,256,0,stream>>>(SQ_ARGS(ws_sl0,ws_sl1,ws_prt0,ws_psc0,ws_red0));
  k_attn<true><<<agrid,256,0,stream>>>(AT_ARGS(ws_red1,ws_prt1,ws_psc1));
  k_fin<<<dim3(NC_,B_*K_),256,0,stream>>>(ws_lgt,ws_red1,ws_fc,ws_sl1,out_slot,out_attn);
}

// Round 9
// 217.056 us; speedup vs baseline: 1.0433x; 1.0274x over previous
//
#include <hip/hip_runtime.h>
#include <stdint.h>

#define B_ 16
#define H_ 64
#define W_ 64
#define D_ 64
#define C_ 16
#define K_ 5
#define N_ 4096
#define NC_ 32         // attention n-chunks
#define CS_ 128        // chunk size = N_/NC_
#define EPS 1e-5f

typedef __attribute__((ext_vector_type(8))) short bf16x8;
typedef __attribute__((ext_vector_type(4))) float f32x4;

__device__ __forceinline__ float wsum64(float v){
  #pragma unroll
  for(int o=1;o<64;o<<=1) v += __shfl_xor(v,o,64);
  return v;
}
__device__ __forceinline__ float wmax64(float v){
  #pragma unroll
  for(int o=1;o<64;o<<=1) v = fmaxf(v, __shfl_xor(v,o,64));
  return v;
}
__device__ __forceinline__ float wmin64(float v){
  #pragma unroll
  for(int o=1;o<64;o<<=1) v = fminf(v, __shfl_xor(v,o,64));
  return v;
}
__device__ __forceinline__ uint16_t f2bf(float f){
  uint32_t u = __float_as_uint(f);
  u += 0x7fffu + ((u>>16)&1u);
  return (uint16_t)(u>>16);
}

// k_pre: fgpos (0-4) + folded biases (5) + fvb/wgx/wgy/gscal/out_slot-zero (6)
// + wrpT (7-22) + gw (23-118) + slot init (119-138)
// + q-side collapse WQ/bq2/vq/csc (139) + gru-side collapse WC/uvec (140)
// Collapse matmuls 4x4 register-blocked; finishers LDS-staged + wave-parallel.
__global__ __launch_bounds__(256) void k_pre(
    const float* __restrict__ mask, const float* __restrict__ noise,
    const float* __restrict__ mu, const float* __restrict__ lsg,
    const float* __restrict__ wm, const float* __restrict__ bm, const float* __restrict__ lnkb,
    const float* __restrict__ wk, const float* __restrict__ wv, const float* __restrict__ lnfb,
    const float* __restrict__ wq, const float* __restrict__ lnqg, const float* __restrict__ lnqb,
    const float* __restrict__ wres, const float* __restrict__ bres,
    const float* __restrict__ lnrg, const float* __restrict__ lnrb,
    const float* __restrict__ wih, const float* __restrict__ whh,
    const float* __restrict__ wg, const float* __restrict__ bg,
    const float* __restrict__ lnfg, const float* __restrict__ lnkg,
    float* __restrict__ ws_fg, float* __restrict__ out_fg,
    float* __restrict__ bm2, float* __restrict__ fkb, float* __restrict__ fvb,
    float* __restrict__ qb, float* __restrict__ br2,
    float* __restrict__ wgx, float* __restrict__ wgy, float* __restrict__ gscal,
    float* __restrict__ wrpT,
    float* __restrict__ gw, float* __restrict__ slot, float* __restrict__ out_slot,
    float* __restrict__ WQp, float* __restrict__ WCp, float* __restrict__ bq2p,
    float* __restrict__ uvp, float* __restrict__ vqp, float* __restrict__ cscp){
  __shared__ __align__(16) float M0[64][68];
  __shared__ __align__(16) float M1[64][68];
  __shared__ __align__(16) float M2T[64][68];
  __shared__ float vtmp[4][64];
  __shared__ float aux[4][64];   // wgx, wgy, bg, lnkg staged from global
  int bid=blockIdx.x, tid=threadIdx.x;

  #define MM44(SRCA, SRCB) { \
    float a4[4], b4[4]; \
    *(float4*)a4 = *(const float4*)(SRCA); \
    *(float4*)b4 = *(const float4*)(SRCB); \
    _Pragma("unroll") \
    for(int ii=0;ii<4;ii++){ \
      _Pragma("unroll") \
      for(int jj=0;jj<4;jj++) acc[ii][jj]=fmaf(a4[ii],b4[jj],acc[ii][jj]); \
    } }

  if(bid<5){
    int k=bid;
    float sm=0.f, sx=0.f, sy=0.f;
    for(int p=tid; p<H_*W_; p+=256){
      int i=p>>6, j=p&63;
      float m = mask[k*H_*W_ + p];
      float x = -1.f + (2.f/63.f)*j;
      float y = -1.f + (2.f/63.f)*i;
      sm+=m; sx+=m*x; sy+=m*y;
    }
    __shared__ float r0[4], r1[4], r2[4];
    int wid=tid>>6, lane=tid&63;
    sm=wsum64(sm); sx=wsum64(sx); sy=wsum64(sy);
    if(lane==0){ r0[wid]=sm; r1[wid]=sx; r2[wid]=sy; }
    __syncthreads();
    if(tid==0){
      float tm=r0[0]+r0[1]+r0[2]+r0[3];
      float tx=r1[0]+r1[1]+r1[2]+r1[3];
      float ty=r2[0]+r2[1]+r2[2]+r2[3];
      float px = tx/(tm+1e-5f), py = ty/(tm+1e-5f);
      ws_fg[k*2+0]=px; ws_fg[k*2+1]=py;
      for(int b=0;b<B_;b++){ out_fg[(b*K_+k)*2+0]=px; out_fg[(b*K_+k)*2+1]=py; }
    }
  } else if(bid==5){
    int sel=tid>>6, o=tid&63; float s=0.f;
    if(sel==0){ s=bm[o]; for(int d=0;d<64;d++) s+=lnkb[d]*wm[o*64+d]; bm2[o]=s; }
    else if(sel==1){ for(int d=0;d<64;d++) s+=lnqb[d]*wq[o*64+d]; qb[o]=0.125f*s; }
    else if(sel==2){ for(int d=0;d<64;d++) s+=lnrb[d]*wres[o*64+d]; br2[o]=s+bres[o]; }
    else { for(int d=0;d<64;d++) s+=lnfb[d]*wk[o*64+d]; fkb[o]=s; }
  } else if(bid==6){
    int wv4=tid>>6, l=tid&63;
    if(wv4==0){ float s=0.f; for(int d=0;d<64;d++) s+=lnfb[d]*wv[l*64+d]; fvb[l]=s; }
    else if(wv4==1){
      float4 w4 = *(const float4*)(wg + l*4);
      wgx[l]=w4.x-w4.z; wgy[l]=w4.y-w4.w;
    } else if(wv4==2){
      float4 w4 = *(const float4*)(wg + l*4);
      float wx=w4.x-w4.z, wy=w4.y-w4.w, bl=bg[l];
      float t;
      t=wsum64(wx);    if(l==0) gscal[0]=t*(1.f/64.f);
      t=wsum64(wy);    if(l==0) gscal[1]=t*(1.f/64.f);
      t=wsum64(bl);    if(l==0) gscal[2]=t*(1.f/64.f);
      t=wsum64(wx*wx); if(l==0) gscal[3]=t*(1.f/64.f);
      t=wsum64(wy*wy); if(l==0) gscal[4]=t*(1.f/64.f);
      t=wsum64(wx*wy); if(l==0) gscal[5]=t*(2.f/64.f);
      t=wsum64(wx*bl); if(l==0) gscal[6]=t*(2.f/64.f);
      t=wsum64(wy*bl); if(l==0) gscal[7]=t*(2.f/64.f);
      t=wsum64(bl*bl); if(l==0) gscal[8]=t*(1.f/64.f);
    } else {
      for(int j=l;j<B_*K_*16;j+=64){ int bk2=j>>4, cc2=j&15; out_slot[bk2*80+64+cc2]=0.f; }
    }
  } else if(bid<23){
    int i=(bid-7)*256+tid;           // < 4096
    int d=i>>6, o=i&63;
    wrpT[i]=lnrg[d]*wres[o*64+d];
  } else if(bid<119){
    int i=(bid-23)*256+tid;          // < 24576
    int g6=i>>12, r=i&4095, d=r>>6, o=r&63;
    float v = (g6<3)? wih[(g6*64+o)*64+d] : whh[((g6-3)*64+o)*64+d];
    gw[g6*4096 + d*64 + o] = v;
  } else if(bid<139){
    int i=(bid-119)*256+tid;
    if(i<B_*K_*D_){ int d=i&63; slot[i]=mu[d]+expf(lsg[d])*noise[i]; }
  } else if(bid==139){
    // q-side collapse: WQ = (0.125*lnqg ∘ wq^T @ wm) @ (lnkg ∘ wk) ∘ lnfg
    for(int i=tid;i<4096;i+=256){ int r=i>>6,c2=i&63; M0[r][c2]=wq[i]; M1[r][c2]=wm[i]; }
    if(tid>=192){ int l=tid-192;
      float4 w4 = *(const float4*)(wg + l*4);
      aux[0][l]=w4.x-w4.z; aux[1][l]=w4.y-w4.w; aux[2][l]=bg[l]; aux[3][l]=lnkg[l];
    }
    __syncthreads();
    if(tid<64){ float s=0.f; for(int d=0;d<64;d++) s+=lnqb[d]*M0[tid][d]; vtmp[0][tid]=0.125f*s; } // qb
    else if(tid<128){ int c2=tid-64; float s=bm[c2]; for(int d=0;d<64;d++) s+=lnkb[d]*M1[c2][d]; vtmp[1][c2]=s; } // bm2
    else if(tid<192){ int o=tid-128; float s=0.f; for(int d=0;d<64;d++) s+=lnfb[d]*wk[o*64+d]; vtmp[2][o]=s; } // fkb
    __syncthreads();
    // M2T[e][d] = P[d][e] = 0.125*lnqg[d]*sum_c wq[c,d]*wm[c,e]   (4x4 blocked)
    {
      int d0=(tid>>4)*4, e0=(tid&15)*4;
      float acc[4][4]={};
      for(int c2=0;c2<64;c2++) MM44(&M0[c2][d0], &M1[c2][e0]);
      float lq4[4]; *(float4*)lq4 = *(const float4*)(lnqg+d0);
      #pragma unroll
      for(int jj=0;jj<4;jj++){
        float w4[4];
        #pragma unroll
        for(int ii=0;ii<4;ii++) w4[ii]=0.125f*lq4[ii]*acc[ii][jj];
        *(float4*)&M2T[e0+jj][d0] = *(float4*)w4;
      }
    }
    __syncthreads();
    if(tid<64){ // vtmp3[e] = sum_c qb[c]*wm[c,e]
      int e=tid; float s=0.f; for(int c2=0;c2<64;c2++) s=fmaf(vtmp[0][c2], M1[c2][e], s); vtmp[3][e]=s;
    } else if(tid<128){ // v4[d] = 0.125*lnqg[d]*sum_c wq[c,d]*bm2[c]
      int d=tid-64; float s=0.f; for(int c2=0;c2<64;c2++) s=fmaf(M0[c2][d], vtmp[1][c2], s);
      vqp[4*64+d]=0.125f*lnqg[d]*s;
    }
    __syncthreads();
    // overwrite M0 with wkL[e][o] = lnkg[e]*wk[e,o]
    for(int i=tid;i<4096;i+=256){ int e=i>>6,o=i&63; M0[e][o]=aux[3][e]*wk[i]; }
    __syncthreads();
    // WQ[d][o] = lnfg[o]*sum_e M2T[e][d]*wkL[e][o]
    {
      int d0=(tid>>4)*4, o0=(tid&15)*4;
      float acc[4][4]={};
      for(int e=0;e<64;e++) MM44(&M2T[e][d0], &M0[e][o0]);
      float lf4[4]; *(float4*)lf4 = *(const float4*)(lnfg+o0);
      #pragma unroll
      for(int ii=0;ii<4;ii++){
        float w4[4];
        #pragma unroll
        for(int jj=0;jj<4;jj++) w4[jj]=lf4[jj]*acc[ii][jj];
        *(float4*)(WQp + (d0+ii)*64 + o0) = *(float4*)w4;
      }
    }
    // finishers: all LDS-resident
    if(tid<64){ int o=tid; float s=0.f;
      for(int e=0;e<64;e++) s=fmaf(vtmp[3][e], M0[e][o], s);
      bq2p[o]=lnfg[o]*s; }
    else if(tid<128){ int d=tid-64; float s1=0.f,sx=0.f,sy=0.f,s3=0.f;
      for(int e=0;e<64;e++){ float pe=M2T[e][d]*aux[3][e];
        s1+=pe; sx+=pe*aux[0][e]; sy+=pe*aux[1][e]; s3+=pe*(aux[2][e]+vtmp[2][e]); }
      vqp[0*64+d]=s1; vqp[1*64+d]=sx; vqp[2*64+d]=sy; vqp[3*64+d]=s3; }
    else if(tid<192){ // wave-parallel csc (wave 2, lane e)
      int e=tid-128;
      float qe=vtmp[3][e]*aux[3][e];
      float c0=wsum64(qe);
      float c1=wsum64(qe*aux[0][e]);
      float c2=wsum64(qe*aux[1][e]);
      float c3=wsum64(qe*(aux[2][e]+vtmp[2][e]));
      float c4=wsum64(vtmp[0][e]*vtmp[1][e]);
      if(e==0){ cscp[0]=c0; cscp[1]=c1; cscp[2]=c2; cscp[3]=c3; cscp[4]=c4; }
    }
  } else {
    // gru-side collapse: WC[d][o] = lnfg[d]*sum_e wv[e,d]*lnkg[e]*wm[o,e]
    for(int i=tid;i<4096;i+=256){ int r=i>>6,c2=i&63; M0[r][c2]=wv[i]*lnkg[r]; M1[c2][r]=wm[i]; }
    if(tid>=192){ int l=tid-192;
      float4 w4 = *(const float4*)(wg + l*4);
      aux[0][l]=w4.x-w4.z; aux[1][l]=w4.y-w4.w; aux[2][l]=bg[l]; aux[3][l]=lnkg[l];
    }
    __syncthreads();
    if(tid<64){ float s=0.f; const float* wr=wv+tid*64;
      for(int d=0;d<64;d++) s+=lnfb[d]*wr[d]; vtmp[0][tid]=s; } // fvb
    __syncthreads();
    {
      int d0=(tid>>4)*4, o0=(tid&15)*4;
      float acc[4][4]={};
      for(int e=0;e<64;e++) MM44(&M0[e][d0], &M1[e][o0]);
      float lf4[4]; *(float4*)lf4 = *(const float4*)(lnfg+d0);
      #pragma unroll
      for(int ii=0;ii<4;ii++){
        float w4[4];
        #pragma unroll
        for(int jj=0;jj<4;jj++) w4[jj]=lf4[ii]*acc[ii][jj];
        *(float4*)(WCp + (d0+ii)*64 + o0) = *(float4*)w4;
      }
    }
    if(tid<64){ int o=tid; float s1=0.f,s2=0.f,s3=0.f,s4=0.f;
      for(int e=0;e<64;e++){ float we=aux[3][e]*M1[e][o];
        s1+=we*(vtmp[0][e]+aux[2][e]); s2+=we*aux[0][e]; s3+=we*aux[1][e]; s4+=we; }
      uvp[0*64+o]=s1; uvp[1*64+o]=s2; uvp[2*64+o]=s3; uvp[3*64+o]=s4; }
  }
  #undef MM44
}

// feat LN -> A (bf16); transient MFMA fk/fv rows -> per-row stat float4s; color LN.
// Tail blocks (bid >= 1024): first-iteration slot preamble (slotq0) per bk.
__global__ __launch_bounds__(256) void k_featln(const float* __restrict__ feat,
    const float* __restrict__ wk, const float* __restrict__ wv, const float* __restrict__ gf,
    const float* __restrict__ fkb, const float* __restrict__ fvb,
    const float* __restrict__ wgx, const float* __restrict__ wgy, const float* __restrict__ bg,
    const float* __restrict__ fc, const float* __restrict__ gc, const float* __restrict__ bc,
    uint16_t* __restrict__ Aout, float4* __restrict__ kstat, float4* __restrict__ vstat,
    float* __restrict__ fcn,
    const float* __restrict__ sl0, const float* __restrict__ WQc,
    const float* __restrict__ bq2c, const float* __restrict__ vqc,
    const float* __restrict__ cscc, const float* __restrict__ gsc,
    uint16_t* __restrict__ qsb, float* __restrict__ cstq){
  int tid=threadIdx.x, wid=tid>>6, lane=tid&63;
  if(blockIdx.x >= (B_*N_)/64){
    // ---- slotq0 tail ----
    __shared__ float vv[64];
    __shared__ float red4[4][64];
    int bk = blockIdx.x - (B_*N_)/64;
    float mwgx=gsc[0], mwgy=gsc[1], mbg=gsc[2];
    if(wid==0){
      float cur = sl0[bk*64+lane];
      float m=wsum64(cur)*(1.f/64.f); float df=cur-m;
      float var=wsum64(df*df)*(1.f/64.f);
      float LNc=df*rsqrtf(var+EPS);
      vv[lane]=LNc;
      float s1=wsum64(LNc*vqc[lane])     + cscc[0];
      float c1=wsum64(LNc*vqc[64+lane])  + cscc[1];
      float c2=wsum64(LNc*vqc[128+lane]) + cscc[2];
      float c3=wsum64(LNc*vqc[192+lane]) + cscc[3];
      float c4=wsum64(LNc*vqc[256+lane]) + cscc[4];
      if(lane==0){
        float* cp = cstq + bk*8;
        cp[0]=c1-s1*mwgx; cp[1]=c2-s1*mwgy; cp[2]=c3-s1*mbg; cp[3]=s1; cp[4]=c4;
      }
    }
    __syncthreads();
    { float p_=0.f;
      #pragma unroll
      for(int dd=0;dd<16;dd++) p_ = fmaf(vv[wid*16+dd], WQc[(wid*16+dd)*64+lane], p_);
      red4[wid][lane]=p_; }
    __syncthreads();
    if(wid==0)
      qsb[bk*64+lane] = f2bf(red4[0][lane]+red4[1][lane]+red4[2][lane]+red4[3][lane] + bq2c[lane]);
    return;
  }
  int q=lane>>4, c=lane&15;
  size_t row = (size_t)blockIdx.x*64 + wid*16 + c;
  const float* xp = feat + row*64;
  float x[16];
  *(float4*)&x[0]  = *(const float4*)(xp + q*8);
  *(float4*)&x[4]  = *(const float4*)(xp + q*8 + 4);
  *(float4*)&x[8]  = *(const float4*)(xp + 32 + q*8);
  *(float4*)&x[12] = *(const float4*)(xp + 36 + q*8);
  float s=0.f;
  #pragma unroll
  for(int i=0;i<16;i++) s+=x[i];
  s += __shfl_xor(s,16,64); s += __shfl_xor(s,32,64);
  float mean = s*(1.f/64.f);
  float v=0.f;
  #pragma unroll
  for(int i=0;i<16;i++){ float d=x[i]-mean; v+=d*d; }
  v += __shfl_xor(v,16,64); v += __shfl_xor(v,32,64);
  float rs = rsqrtf(v*(1.f/64.f)+EPS);
  float gl[16];
  *(float4*)&gl[0]  = *(const float4*)(gf + q*8);
  *(float4*)&gl[4]  = *(const float4*)(gf + q*8 + 4);
  *(float4*)&gl[8]  = *(const float4*)(gf + 32 + q*8);
  *(float4*)&gl[12] = *(const float4*)(gf + 36 + q*8);
  bf16x8 A0, A1;
  #pragma unroll
  for(int j=0;j<8;j++){
    A0[j] = (short)f2bf((x[j]  -mean)*rs);
    A1[j] = (short)f2bf((x[8+j]-mean)*rs);
  }
  *(bf16x8*)(Aout + row*64 + q*8) = A0;
  *(bf16x8*)(Aout + row*64 + 32 + q*8) = A1;
  float wgxl[4][4], wgyl[4][4], bgl[4][4];
  #pragma unroll
  for(int ot=0;ot<4;ot++){
    *(float4*)&wgxl[ot][0] = *(const float4*)(wgx + ot*16 + q*4);
    *(float4*)&wgyl[ot][0] = *(const float4*)(wgy + ot*16 + q*4);
    *(float4*)&bgl[ot][0]  = *(const float4*)(bg + ot*16 + q*4);
  }
  #pragma unroll
  for(int mat=0;mat<2;mat++){
    const float* w = mat? wv : wk;
    const float* fb = mat? fvb : fkb;
    float ss=0.f, s2=0.f, dx=0.f, dy=0.f, db=0.f;
    #pragma unroll
    for(int ot=0; ot<4; ot++){
      const float* wp = w + (size_t)(ot*16+c)*64 + q*8;
      bf16x8 W0, W1;
      #pragma unroll
      for(int j=0;j<8;j++){ W0[j]=(short)f2bf(wp[j]*gl[j]); W1[j]=(short)f2bf(wp[32+j]*gl[8+j]); }
      float4 bq = *(const float4*)(fb + ot*16 + q*4);
      f32x4 acc = {bq.x,bq.y,bq.z,bq.w};
      acc = __builtin_amdgcn_mfma_f32_16x16x32_bf16(W0, A0, acc, 0,0,0);
      acc = __builtin_amdgcn_mfma_f32_16x16x32_bf16(W1, A1, acc, 0,0,0);
      #pragma unroll
      for(int r=0;r<4;r++){
        float a=acc[r];
        ss+=a; s2+=a*a;
        dx = fmaf(a, wgxl[ot][r], dx);
        dy = fmaf(a, wgyl[ot][r], dy);
        db = fmaf(a, bgl[ot][r], db);
      }
    }
    ss += __shfl_xor(ss,16,64); ss += __shfl_xor(ss,32,64);
    s2 += __shfl_xor(s2,16,64); s2 += __shfl_xor(s2,32,64);
    dx += __shfl_xor(dx,16,64); dx += __shfl_xor(dx,32,64);
    dy += __shfl_xor(dy,16,64); dy += __shfl_xor(dy,32,64);
    db += __shfl_xor(db,16,64); db += __shfl_xor(db,32,64);
    if(lane<16){
      size_t row2 = (size_t)blockIdx.x*64 + wid*16 + lane;
      float4 st = { ss*(1.f/64.f), s2*(1.f/64.f)+db*(1.f/32.f), dx*(1.f/32.f), dy*(1.f/32.f) };
      (mat? vstat : kstat)[row2] = st;
    }
  }
  int r16=tid>>4, cc=tid&15;
  #pragma unroll
  for(int i=0;i<4;i++){
    size_t row2 = (size_t)blockIdx.x*64 + i*16 + r16;
    float xv = fc[row2*16+cc];
    float sc=xv;
    #pragma unroll
    for(int o=1;o<16;o<<=1) sc += __shfl_xor(sc,o,16);
    float m2 = sc*(1.f/16.f);
    float df = xv-m2;
    float v2 = df*df;
    #pragma unroll
    for(int o=1;o<16;o<<=1) v2 += __shfl_xor(v2,o,16);
    fcn[row2*16+cc] = df*rsqrtf(v2*(1.f/16.f)+EPS)*gc[cc] + bc[cc];
  }
}

// Block-parallel per-bk GRU preamble: collapsed merge + single-matvec q chain.
// 80 blocks x 256 threads. qs written as bf16.
__global__ __launch_bounds__(256) void k_slotq(
    const float* __restrict__ slot_prev, float* __restrict__ slot_cur,
    const float* __restrict__ part, const float* __restrict__ pscal,
    const float* __restrict__ red_in,
    const float* __restrict__ gw,
    const float* __restrict__ bih, const float* __restrict__ bhh,
    const float* __restrict__ wrpT, const float* __restrict__ br2,
    const float* __restrict__ bm2,
    const float* __restrict__ WQ, const float* __restrict__ bq2,
    const float* __restrict__ WC, const float* __restrict__ uvec,
    const float* __restrict__ vq, const float* __restrict__ csc,
    const float* __restrict__ gscal,
    uint16_t* __restrict__ qs_out, float* __restrict__ cst_out){
  __shared__ float vv[64], vh[64];
  __shared__ float red6[4][64][6];
  __shared__ float lamb[NC_];
  __shared__ float sc4[4];
  int bk=blockIdx.x;
  int tid=threadIdx.x, wid=tid>>6, lane=tid&63;
  int o=lane, qq=wid;
  float mwgx=gscal[0], mwgy=gscal[1], mbg=gscal[2];

  #define MV(Wptr) { float p_=0.f; \
      _Pragma("unroll") \
      for(int dd=0;dd<16;dd++) p_ = fmaf(vv[qq*16+dd], (Wptr)[(qq*16+dd)*64+o], p_); \
      red6[qq][o][0]=p_; } __syncthreads();
  #define SUM0 (red6[0][lane][0]+red6[1][lane][0]+red6[2][lane][0]+red6[3][lane][0])

  float cur=0.f, hp=0.f;
  {
    if(wid==0){
      // lane-parallel chunk merge (lane<NC_)
      float m_l = (lane<NC_)? red_in[((size_t)bk*NC_+lane)*4]   : -1e30f;
      float s_l = (lane<NC_)? red_in[((size_t)bk*NC_+lane)*4+1] : 0.f;
      float M = wmax64(m_l);
      float eu = (lane<NC_)? __expf(m_l-M) : 0.f;
      float S = wsum64(s_l*eu);
      float lam = eu/S;
      if(lane<NC_) lamb[lane]=lam;
      float p0 = (lane<NC_)? pscal[((size_t)bk*NC_+lane)*4+0] : 0.f;
      float p1 = (lane<NC_)? pscal[((size_t)bk*NC_+lane)*4+1] : 0.f;
      float p2 = (lane<NC_)? pscal[((size_t)bk*NC_+lane)*4+2] : 0.f;
      float p3 = (lane<NC_)? pscal[((size_t)bk*NC_+lane)*4+3] : 0.f;
      float As = wsum64(lam*p0), Ax = wsum64(lam*p1);
      float Ay = wsum64(lam*p2), Am = wsum64(lam*p3);
      if(lane==0){ sc4[0]=As; sc4[1]=Ax; sc4[2]=Ay; sc4[3]=Am; }
    }
    __syncthreads();
    { // sA partials: wave qq handles chunks qq*8..qq*8+7
      float p_=0.f;
      #pragma unroll
      for(int j=0;j<8;j++){
        int cc = qq*8+j;
        p_ = fmaf(lamb[cc], part[((size_t)bk*NC_+cc)*64+o], p_);
      }
      red6[qq][o][0]=p_;
    }
    __syncthreads();
    if(wid==0) vv[lane] = SUM0;        // sA (WC absorbs lnfg)
    __syncthreads();
    MV(WC);
    if(wid==0){
      float As=sc4[0],Ax=sc4[1],Ay=sc4[2],Am=sc4[3];
      float x_ = SUM0 + As*uvec[lane] + Ax*uvec[64+lane] + Ay*uvec[128+lane]
               - Am*uvec[192+lane] + bm2[lane];
      hp = slot_prev[bk*64+lane];
      vv[lane]=x_; vh[lane]=hp;
    }
    __syncthreads();
    {
      float p0=0.f,p1=0.f,p2=0.f,p3=0.f,p4=0.f,p5=0.f;
      #pragma unroll
      for(int dd=0;dd<16;dd++){
        int d = qq*16+dd;
        float xd=vv[d], hd=vh[d];
        p0 = fmaf(xd, gw[d*64+o], p0);
        p1 = fmaf(xd, gw[4096+d*64+o], p1);
        p2 = fmaf(xd, gw[8192+d*64+o], p2);
        p3 = fmaf(hd, gw[12288+d*64+o], p3);
        p4 = fmaf(hd, gw[16384+d*64+o], p4);
        p5 = fmaf(hd, gw[20480+d*64+o], p5);
      }
      red6[qq][o][0]=p0; red6[qq][o][1]=p1; red6[qq][o][2]=p2;
      red6[qq][o][3]=p3; red6[qq][o][4]=p4; red6[qq][o][5]=p5;
    }
    __syncthreads();
    if(wid==0){
      float gir=bih[lane], giz=bih[64+lane], gin=bih[128+lane];
      float ghr=bhh[lane], ghz=bhh[64+lane], ghn=bhh[128+lane];
      #pragma unroll
      for(int w=0;w<4;w++){
        gir+=red6[w][lane][0]; giz+=red6[w][lane][1]; gin+=red6[w][lane][2];
        ghr+=red6[w][lane][3]; ghz+=red6[w][lane][4]; ghn+=red6[w][lane][5];
      }
      float r=1.f/(1.f+__expf(-(gir+ghr)));
      float z=1.f/(1.f+__expf(-(giz+ghz)));
      float nn=tanhf(gin+r*ghn);
      float sp=(1.f-z)*nn+z*hp;
      float m=wsum64(sp)*(1.f/64.f); float df=sp-m;
      float var=wsum64(df*df)*(1.f/64.f);
      vv[lane]=df*rsqrtf(var+EPS);
    }
    __syncthreads();
    MV(wrpT);
    if(wid==0){
      cur = SUM0 + br2[lane] + hp;
      slot_cur[bk*64+lane]=cur;
    }
  }
  __syncthreads();
  if(wid==0){
    float m=wsum64(cur)*(1.f/64.f); float df=cur-m;
    float var=wsum64(df*df)*(1.f/64.f);
    float LNc=df*rsqrtf(var+EPS);
    vv[lane]=LNc;
    float s1=wsum64(LNc*vq[lane])     + csc[0];
    float c1=wsum64(LNc*vq[64+lane])  + csc[1];
    float c2=wsum64(LNc*vq[128+lane]) + csc[2];
    float c3=wsum64(LNc*vq[192+lane]) + csc[3];
    float c4=wsum64(LNc*vq[256+lane]) + csc[4];
    if(lane==0){
      float* cp = cst_out + bk*8;
      cp[0]=c1-s1*mwgx; cp[1]=c2-s1*mwgy; cp[2]=c3-s1*mbg; cp[3]=s1; cp[4]=c4;
    }
  }
  __syncthreads();
  MV(WQ);
  if(wid==0) qs_out[bk*64+lane] = f2bf(SUM0 + bq2[lane]);
  #undef MV
  #undef SUM0
}

// Slot-amortized attention: block = (chunk CS_=128, b), all K=5 slots.
// Phase 2 split across all 4 waves: waves 0-1 -> slots 0-2, waves 2-3 -> slots 3-4.
// No LDS A-staging (accumulation reads L2-hot global); no prologue barrier.
// Grid (NC_=32, B_) = 512 blocks.
template<bool FINAL>
__global__ __launch_bounds__(256) void k_attn(const uint16_t* __restrict__ Aw,
    const float4* __restrict__ kstat, const float4* __restrict__ vstat,
    const uint16_t* __restrict__ qsg, const float* __restrict__ cstg,
    const float* __restrict__ gscal, const float* __restrict__ ws_fg,
    float* __restrict__ lgt, float* __restrict__ red_out,
    float* __restrict__ part_o, float* __restrict__ pscal_o){
  __shared__ __align__(16) float dps[5][CS_+4];  // dots -> weights
  __shared__ float pw[4][5][64];
  __shared__ float rm[2][5], rn[2][5];
  __shared__ float rsc[2][5][5];
  __shared__ float cstl[5][5];
  __shared__ float fgl[5][2];
  int chunk=blockIdx.x, b=blockIdx.y;
  int tid=threadIdx.x, wid=tid>>6, lane=tid&63;
  int c=lane&15, q=lane>>4;
  float mwgx=gscal[0], mwgy=gscal[1], mbg=gscal[2];
  float g1=gscal[3], g2=gscal[4], g3=gscal[5], g4=gscal[6], g5=gscal[7], g6=gscal[8];

  if(tid<25) cstl[tid/5][tid%5] = cstg[(b*K_ + tid/5)*8 + (tid%5)];
  if(tid>=32 && tid<42){ int i2=tid-32; fgl[i2>>1][i2&1] = ws_fg[i2]; }
  // phase-2 mapping: all threads active. half=row-half, slots by wave pair.
  int half = wid & 1;
  int r128 = half*64 + lane;            // row within chunk
  int nrow = chunk*CS_ + r128;
  int k0 = (wid < 2) ? 0 : 3;
  int nk = (wid < 2) ? 3 : 2;
  float4 st = kstat[(size_t)b*N_ + nrow];
  float4 sv;
  if(!FINAL) sv = vstat[(size_t)b*N_ + nrow];
  float gx = -1.f + (2.f/63.f)*(nrow&63);
  float gy = -1.f + (2.f/63.f)*(nrow>>6);

  // phase 1: MFMA dots; B-frags from GLOBAL (aligned); 2 tiles per wave.
  // (no barrier needed before this: phase 1 touches only dps + global)
  {
    bf16x8 QF0={0,0,0,0,0,0,0,0}, QF1={0,0,0,0,0,0,0,0};
    if(c<5){
      const uint16_t* qpp = qsg + (b*K_+c)*64;
      QF0 = *(const bf16x8*)(qpp + q*8);
      QF1 = *(const bf16x8*)(qpp + 32 + q*8);
    }
    const uint16_t* Abase = Aw + ((size_t)b*N_ + chunk*CS_)*64;
    #pragma unroll
    for(int it=0;it<2;it++){
      int tile = wid*32 + it*16;
      const uint16_t* rp = Abase + (size_t)(tile+c)*64;
      bf16x8 BF0 = *(const bf16x8*)(rp + q*8);
      bf16x8 BF1 = *(const bf16x8*)(rp + 32 + q*8);
      f32x4 acc = {0.f,0.f,0.f,0.f};
      acc = __builtin_amdgcn_mfma_f32_16x16x32_bf16(QF0, BF0, acc, 0,0,0);
      acc = __builtin_amdgcn_mfma_f32_16x16x32_bf16(QF1, BF1, acc, 0,0,0);
      #pragma unroll
      for(int r=0;r<4;r++){
        int s = q*4+r;
        if(s<5) dps[s][tile+c]=acc[r];
      }
    }
  }
  __syncthreads();

  // phase 2a: logits + per-half max (per-thread serial chain: <=3 slots)
  float l3[3], w3[3];
  #pragma unroll
  for(int j=0;j<3;j++){
    if(j<nk){
      int k=k0+j;
      float rx = gx - fgl[k][0], ry = gy - fgl[k][1];
      float CX=cstl[k][0], CY=cstl[k][1], C0=cstl[k][2], S1=cstl[k][3], C4=cstl[k][4];
      float quad = g1*rx*rx + g2*ry*ry + g3*rx*ry + g4*rx + g5*ry + g6;
      float mu = st.x + rx*mwgx + ry*mwgy + mbg;
      float var = st.y + rx*st.z + ry*st.w + quad - mu*mu;
      float rsn = rsqrtf(var+EPS);
      float l = rsn*(dps[k][r128] + rx*CX + ry*CY + C0 - S1*st.x) + C4;
      l3[j]=l;
      float wmx = wmax64(l);
      if(lane==0) rm[half][k]=wmx;
      if(FINAL){ float mn=wmin64(l); if(lane==0) rn[half][k]=mn; }
    }
  }
  __syncthreads();
  // phase 2b: exp + weighted sums
  #pragma unroll
  for(int j=0;j<3;j++){
    if(j<nk){
      int k=k0+j;
      float m_c = fmaxf(rm[0][k], rm[1][k]);
      float e = __expf(l3[j]-m_c);
      float scq = wsum64(e);
      if(!FINAL){
        float rx = gx - fgl[k][0], ry = gy - fgl[k][1];
        float quad = g1*rx*rx + g2*ry*ry + g3*rx*ry + g4*rx + g5*ry + g6;
        float muV = sv.x + rx*mwgx + ry*mwgy + mbg;
        float varV = sv.y + rx*sv.z + ry*sv.w + quad - muV*muV;
        float rsv_ = rsqrtf(varV+EPS);
        float w_ = e*rsv_;
        w3[j]=w_;
        float As2=wsum64(w_), Ax2=wsum64(w_*rx), Ay2=wsum64(w_*ry), Am2=wsum64(w_*muV);
        if(lane==0){ rsc[half][k][0]=scq; rsc[half][k][1]=As2; rsc[half][k][2]=Ax2;
                     rsc[half][k][3]=Ay2; rsc[half][k][4]=Am2; }
      } else {
        lgt[(size_t)(b*K_+k)*N_ + nrow] = l3[j];
        if(lane==0) rsc[half][k][0]=scq;
      }
    }
  }
  __syncthreads();
  if(tid<5){
    int k=tid;
    size_t idx = ((size_t)(b*K_+k)*NC_+chunk)*4;
    red_out[idx+0]=fmaxf(rm[0][k],rm[1][k]);
    red_out[idx+1]=rsc[0][k][0]+rsc[1][k][0];
    if(FINAL) red_out[idx+2]=fminf(rn[0][k],rn[1][k]);
    if(!FINAL){
      pscal_o[idx+0]=rsc[0][k][1]+rsc[1][k][1];
      pscal_o[idx+1]=rsc[0][k][2]+rsc[1][k][2];
      pscal_o[idx+2]=rsc[0][k][3]+rsc[1][k][3];
      pscal_o[idx+3]=rsc[0][k][4]+rsc[1][k][4];
    }
  }
  if(!FINAL){
    #pragma unroll
    for(int j=0;j<3;j++)
      if(j<nk) dps[k0+j][r128]=w3[j];
  }

  // accumulation: part[k][ch] = sum_row w_k[row]*A[row][ch]
  // A read directly from global (L2-hot, lane-contiguous 128B per row).
  if(!FINAL){
    __syncthreads();
    const uint16_t* Abase = Aw + ((size_t)b*N_ + chunk*CS_)*64;
    float a0=0.f,a1=0.f,a2=0.f,a3=0.f,a4=0.f;
    #pragma unroll
    for(int rb=0;rb<8;rb++){
      int row0 = wid*32 + rb*4;
      float4 d0 = *(const float4*)&dps[0][row0];
      float4 d1 = *(const float4*)&dps[1][row0];
      float4 d2 = *(const float4*)&dps[2][row0];
      float4 d3 = *(const float4*)&dps[3][row0];
      float4 d4 = *(const float4*)&dps[4][row0];
      float av0 = __uint_as_float(((uint32_t)Abase[(size_t)(row0+0)*64+lane])<<16);
      float av1 = __uint_as_float(((uint32_t)Abase[(size_t)(row0+1)*64+lane])<<16);
      float av2 = __uint_as_float(((uint32_t)Abase[(size_t)(row0+2)*64+lane])<<16);
      float av3 = __uint_as_float(((uint32_t)Abase[(size_t)(row0+3)*64+lane])<<16);
      a0=fmaf(d0.x,av0,a0); a0=fmaf(d0.y,av1,a0); a0=fmaf(d0.z,av2,a0); a0=fmaf(d0.w,av3,a0);
      a1=fmaf(d1.x,av0,a1); a1=fmaf(d1.y,av1,a1); a1=fmaf(d1.z,av2,a1); a1=fmaf(d1.w,av3,a1);
      a2=fmaf(d2.x,av0,a2); a2=fmaf(d2.y,av1,a2); a2=fmaf(d2.z,av2,a2); a2=fmaf(d2.w,av3,a2);
      a3=fmaf(d3.x,av0,a3); a3=fmaf(d3.y,av1,a3); a3=fmaf(d3.z,av2,a3); a3=fmaf(d3.w,av3,a3);
      a4=fmaf(d4.x,av0,a4); a4=fmaf(d4.y,av1,a4); a4=fmaf(d4.z,av2,a4); a4=fmaf(d4.w,av3,a4);
    }
    pw[wid][0][lane]=a0; pw[wid][1][lane]=a1; pw[wid][2][lane]=a2;
    pw[wid][3][lane]=a3; pw[wid][4][lane]=a4;
    __syncthreads();
    if(tid<64){
      #pragma unroll
      for(int k=0;k<5;k++){
        float s2 = pw[0][k][tid]+pw[1][k][tid]+pw[2][k][tid]+pw[3][k][tid];
        part_o[((size_t)(b*K_+k)*NC_+chunk)*64 + tid] = s2;
      }
    }
  }
}

// fin: p from global stats; out_attn; color partial atomicAdd; slot write (chunk 0)
__global__ __launch_bounds__(256) void k_fin(const float* __restrict__ lgt,
    const float* __restrict__ red, const float* __restrict__ featc,
    const float* __restrict__ sl1, float* __restrict__ out_slot,
    float* __restrict__ out_attn){
  __shared__ float psp[CS_];
  __shared__ float pcz[4][16];
  int chunk=blockIdx.x, bk=blockIdx.y, b=bk/K_;
  int tid=threadIdx.x, wid=tid>>6, lane=tid&63, sub=lane>>4, c4=lane&15;
  const float* rp = red + (size_t)bk*NC_*4;
  float M=-1e30f;
  #pragma unroll
  for(int i=0;i<NC_;i++) M = fmaxf(M, rp[i*4]);
  float S=0.f;
  #pragma unroll
  for(int i=0;i<NC_;i++) S += rp[i*4+1]*__expf(rp[i*4]-M);
  float invS = 1.f/S;
  float LMIN=1e30f;
  #pragma unroll
  for(int i=0;i<NC_;i++) LMIN=fminf(LMIN, rp[i*4+2]);
  float amin = __expf(LMIN-M)*invS;
  float dinv = 1.f/(invS - amin + 1e-5f);
  const float* lp = lgt + (size_t)bk*N_ + chunk*CS_;
  if(tid<CS_){
    float p = __expf(lp[tid]-M)*invS;
    psp[tid]=p;
    out_attn[(size_t)bk*N_ + chunk*CS_ + tid] = (p - amin)*dinv;
  }
  __syncthreads();
  const float* Fb = featc + ((size_t)b*N_ + chunk*CS_)*16;
  float ac=0.f;
  for(int t=0;t<8;t++){
    int n = wid*32 + t*4 + sub;
    ac += psp[n]*Fb[(size_t)n*16 + c4];
  }
  ac+=__shfl_xor(ac,16,64); ac+=__shfl_xor(ac,32,64);
  if(lane<16) pcz[wid][lane]=ac;
  __syncthreads();
  if(tid<16){
    float s2 = pcz[0][tid]+pcz[1][tid]+pcz[2][tid]+pcz[3][tid];
    atomicAdd(&out_slot[bk*80+64+tid], s2);
  }
  if(chunk==0 && tid<64) out_slot[bk*80+tid]=sl1[bk*64+tid];
}

extern "C" void kernel_launch(void* const* d_in, const int* in_sizes, int n_in,
                              void* d_out, int out_size, void* d_ws, size_t ws_size,
                              hipStream_t stream){
  (void)in_sizes; (void)n_in; (void)out_size; (void)ws_size;
  const float* feat = (const float*)d_in[0];
  const float* featc= (const float*)d_in[1];
  const float* mask = (const float*)d_in[2];
  const float* noise= (const float*)d_in[3];
  const float* mu   = (const float*)d_in[4];
  const float* lsg  = (const float*)d_in[5];
  const float* wg   = (const float*)d_in[6];
  const float* bg   = (const float*)d_in[7];
  const float* wk   = (const float*)d_in[8];
  const float* wv   = (const float*)d_in[9];
  const float* lnkg = (const float*)d_in[10];
  const float* lnkb = (const float*)d_in[11];
  const float* wm   = (const float*)d_in[12];
  const float* bm   = (const float*)d_in[13];
  const float* lnqg = (const float*)d_in[14];
  const float* lnqb = (const float*)d_in[15];
  const float* wq   = (const float*)d_in[16];
  const float* wih  = (const float*)d_in[17];
  const float* whh  = (const float*)d_in[18];
  const float* bih  = (const float*)d_in[19];
  const float* bhh  = (const float*)d_in[20];
  const float* lnfg = (const float*)d_in[21];
  const float* lnfb = (const float*)d_in[22];
  const float* lncg = (const float*)d_in[23];
  const float* lncb = (const float*)d_in[24];
  const float* lnrg = (const float*)d_in[25];
  const float* lnrb = (const float*)d_in[26];
  const float* wres = (const float*)d_in[27];
  const float* bres = (const float*)d_in[28];

  float* out = (float*)d_out;
  float* out_slot = out;          // (B,K,80)
  float* out_fg   = out + 6400;   // (B,K,2)
  float* out_attn = out + 6560;   // (B,K,N)

  float* wsf     = (float*)d_ws;
  float* ws_fg   = wsf;                                // 16
  float* ws_bm2  = wsf + 16;                           // 64
  float* ws_fkb  = ws_bm2 + 64;                        // 64
  float* ws_fvb  = ws_fkb + 64;                        // 64
  float* ws_qb   = ws_fvb + 64;                        // 64
  float* ws_br2  = ws_qb + 64;                         // 64
  float* ws_wgx  = ws_br2 + 64;                        // 64
  float* ws_wgy  = ws_wgx + 64;                        // 64
  float* ws_gs   = ws_wgy + 64;                        // 16
  float* ws_wrpT = ws_gs + 16;                         // 4096
  float* ws_gw   = ws_wrpT + 4096;                     // 24576
  float* ws_WQ   = ws_gw + 24576;                      // 4096
  float* ws_WC   = ws_WQ + 4096;                       // 4096
  float* ws_bq2  = ws_WC + 4096;                       // 64
  float* ws_u    = ws_bq2 + 64;                        // 256
  float* ws_vq   = ws_u + 256;                         // 320
  float* ws_csc  = ws_vq + 320;                        // 16
  uint16_t* ws_qsb = (uint16_t*)(ws_csc + 16);         // 5120 bf16 (in 5120-float slot)
  float* ws_cst  = ws_csc + 16 + 5120;                 // 640
  float* ws_fc   = ws_cst + 640;                       // B*N*C
  float* ws_sl0  = ws_fc + (size_t)B_*N_*C_;           // 5120
  float* ws_sl1  = ws_sl0 + B_*K_*D_;                  // 5120
  float* ws_lgt  = ws_sl1 + B_*K_*D_;                  // B*K*N
  float* ws_red0 = ws_lgt + (size_t)B_*K_*N_;          // 80*NC*4
  float* ws_red1 = ws_red0 + B_*K_*NC_*4;              // 80*NC*4
  float* ws_prt0 = ws_red1 + B_*K_*NC_*4;              // 80*NC*64
  float* ws_prt1 = ws_prt0 + (size_t)B_*K_*NC_*64;     // 80*NC*64
  float* ws_psc0 = ws_prt1 + (size_t)B_*K_*NC_*64;     // 80*NC*4
  float* ws_psc1 = ws_psc0 + B_*K_*NC_*4;              // 80*NC*4
  float4* ws_kst = (float4*)(ws_psc1 + B_*K_*NC_*4);   // B*N float4
  float4* ws_vst = ws_kst + (size_t)B_*N_;             // B*N float4
  uint16_t* ws_A = (uint16_t*)(ws_vst + (size_t)B_*N_);// B*N*64 bf16

  k_pre<<<141,256,0,stream>>>(mask,noise,mu,lsg, wm,bm,lnkb, wk,wv,lnfb,
                              wq,lnqg,lnqb, wres,bres,lnrg,lnrb, wih,whh, wg,bg,
                              lnfg,lnkg,
                              ws_fg,out_fg, ws_bm2,ws_fkb,ws_fvb,ws_qb,ws_br2,
                              ws_wgx,ws_wgy,ws_gs,
                              ws_wrpT, ws_gw, ws_sl0, out_slot,
                              ws_WQ, ws_WC, ws_bq2, ws_u, ws_vq, ws_csc);
  // featln + slotq0 tail (80 extra blocks)
  k_featln<<<(B_*N_)/64 + B_*K_,256,0,stream>>>(feat,wk,wv,lnfg,ws_fkb,ws_fvb,
                                        ws_wgx,ws_wgy,bg,
                                        featc,lncg,lncb,
                                        ws_A,ws_kst,ws_vst,ws_fc,
                                        ws_sl0, ws_WQ, ws_bq2, ws_vq, ws_csc, ws_gs,
                                        ws_qsb, ws_cst);

  dim3 agrid(NC_,B_);
  #define SQ_ARGS(SPREV,SCUR,PIN,SCIN,RIN) SPREV,SCUR,PIN,SCIN,RIN,ws_gw, \
      bih,bhh,ws_wrpT,ws_br2,ws_bm2, ws_WQ,ws_bq2, ws_WC,ws_u, ws_vq,ws_csc, \
      ws_gs, ws_qsb,ws_cst
  #define AT_ARGS(ROUT,POUT,SCOUT) ws_A,ws_kst,ws_vst,ws_qsb,ws_cst,ws_gs,ws_fg, \
      ws_lgt,ROUT,POUT,SCOUT

  k_attn<false><<<agrid,256,0,stream>>>(AT_ARGS(ws_red0,ws_prt0,ws_psc0));
  k_slotq<<<B_*K_,256,0,stream>>>(SQ_ARGS(ws_sl0,ws_sl1,ws_prt0,ws_psc0,ws_red0));
  k_attn<false><<<agrid,256,0,stream>>>(AT_ARGS(ws_red1,ws_prt1,ws_psc1));
  k_slotq<<<B_*K_,256,0,stream>>>(SQ_ARGS(ws_sl1,ws_sl0,ws_prt1,ws_psc1,ws_red1));
  k_attn<false><<<agrid,256,0,stream>>>(AT_ARGS(ws_red0,ws_prt0,ws_psc0));
  k_slotq<<<B_*K_,256,0,stream>>>(SQ_ARGS(ws_sl0,ws_sl1,ws_prt0,ws_psc0,ws_red0));
  k_attn<true><<<agrid,256,0,stream>>>(AT_ARGS(ws_red1,ws_prt1,ws_psc1));
  k_fin<<<dim3(NC_,B_*K_),256,0,stream>>>(ws_lgt,ws_red1,ws_fc,ws_sl1,out_slot,out_attn);
}